// Round 12
// baseline (424.897 us; speedup 1.0000x reference)
//
#include <hip/hip_runtime.h>
#include <stdint.h>

typedef unsigned short u16;
typedef long i64;
typedef __bf16 bf16x8 __attribute__((ext_vector_type(8)));
typedef float f32x4 __attribute__((ext_vector_type(4)));
typedef float f32x16 __attribute__((ext_vector_type(16)));
typedef int v8i __attribute__((ext_vector_type(8)));
typedef uint32_t u32x2 __attribute__((ext_vector_type(2)));
typedef uint32_t u32x4 __attribute__((ext_vector_type(4)));

#define NB 4
#define NC 512
#define NG 32
#define NSEQ 4096
#define NM (NB*NSEQ)

#define MFMA_(a,b,c) __builtin_amdgcn_mfma_f32_16x16x32_bf16(a,b,c,0,0,0)
#define MFMA8_(a,b,c) __builtin_amdgcn_mfma_f32_16x16x32_fp8_fp8(a,b,c,0,0,0)
// MX-scaled 32x32x64 fp8xfp8, unit scales (e8m0 127 = 1.0): numerics identical
#define MFMAX_(a,b,c) __builtin_amdgcn_mfma_scale_f32_32x32x64_f8f6f4(a,b,c,0,0,0,127,0,127)

__device__ __forceinline__ u16 f2bf(float f){
  uint32_t u = __builtin_bit_cast(uint32_t, f);
  u += 0x7FFFu + ((u >> 16) & 1u);
  return (u16)(u >> 16);
}
__device__ __forceinline__ float bfu(uint32_t lo16){
  return __builtin_bit_cast(float, lo16 << 16);
}
__device__ __forceinline__ uint32_t pk2(float a, float b){
  return (uint32_t)f2bf(a) | ((uint32_t)f2bf(b) << 16);
}

__device__ __forceinline__ void gll16(const void* g, void* l){
  __builtin_amdgcn_global_load_lds(
      (const __attribute__((address_space(1))) void*)g,
      (__attribute__((address_space(3))) void*)l, 16, 0, 0);
}

__global__ void k_zero(float* p, int n){
  int i = blockIdx.x*blockDim.x + threadIdx.x;
  if (i < n) p[i] = 0.f;
}

// GN pass 1: row-major read of x, per-group partial sums + bf16 copy of x.
__global__ __launch_bounds__(256) void k_gn_stats2(const float* __restrict__ x,
    u16* __restrict__ xbf, float* __restrict__ stats){
  int blk = blockIdx.x;
  int b = blk >> 6, ch = blk & 63;
  int t = threadIdx.x;
  int colv = t & 127;
  int r0 = ch*64 + (t >> 7);
  const float* xp = x  + (size_t)b*NSEQ*NC + (size_t)r0*NC + colv*4;
  u16* xb       = xbf + (size_t)b*NSEQ*NC + (size_t)r0*NC + colv*4;
  float s1 = 0.f, s2 = 0.f;
  #pragma unroll 4
  for (int i = 0; i < 32; i++){
    float4 v = *(const float4*)(xp + (size_t)i*2*NC);
    s1 += v.x+v.y+v.z+v.w;
    s2 += v.x*v.x+v.y*v.y+v.z*v.z+v.w*v.w;
    ushort4 o; o.x=f2bf(v.x); o.y=f2bf(v.y); o.z=f2bf(v.z); o.w=f2bf(v.w);
    *(ushort4*)(xb + (size_t)i*2*NC) = o;
  }
  s1 += __shfl_xor(s1,1); s2 += __shfl_xor(s2,1);
  s1 += __shfl_xor(s1,2); s2 += __shfl_xor(s2,2);
  __shared__ float ls1[4][16], ls2[4][16];
  int w = t >> 6, l = t & 63;
  if ((l & 3) == 0){ ls1[w][l>>2] = s1; ls2[w][l>>2] = s2; }
  __syncthreads();
  if (t < 32){
    int g = t;
    int wlo = g >> 4;
    float a1 = ls1[wlo][g&15] + ls1[wlo+2][g&15];
    float a2 = ls2[wlo][g&15] + ls2[wlo+2][g&15];
    atomicAdd(&stats[(b*NG+g)*2+0], a1);
    atomicAdd(&stats[(b*NG+g)*2+1], a2);
  }
}

// GN pass 2: read bf16 x-copy, normalize+affine, write hn.
__global__ __launch_bounds__(256) void k_gn_apply2(const u16* __restrict__ xbf,
    const float* __restrict__ stats, const float* __restrict__ gsc,
    const float* __restrict__ gbi, u16* __restrict__ hn){
  const float inv_cnt = 1.f/((float)NSEQ*16.f);
  size_t i = ((size_t)blockIdx.x*256 + threadIdx.x)*8;
  int c = (int)(i & 511);
  int b = (int)(i >> 21);
  int g = c >> 4;
  float s1 = stats[(b*NG+g)*2], s2 = stats[(b*NG+g)*2+1];
  float mean = s1*inv_cnt;
  float rstd = rsqrtf(s2*inv_cnt - mean*mean + 1e-6f);
  u32x4 v = *(const u32x4*)(xbf + i);
  float4 scA = *(const float4*)(gsc + c), scB = *(const float4*)(gsc + c + 4);
  float4 biA = *(const float4*)(gbi + c), biB = *(const float4*)(gbi + c + 4);
  const float sc[8] = {scA.x,scA.y,scA.z,scA.w,scB.x,scB.y,scB.z,scB.w};
  const float bi[8] = {biA.x,biA.y,biA.z,biA.w,biB.x,biB.y,biB.z,biB.w};
  u32x4 o;
  #pragma unroll
  for (int j = 0; j < 4; j++){
    float lo = bfu(v[j] & 0xFFFFu);
    float hi = __builtin_bit_cast(float, v[j] & 0xFFFF0000u);
    o[j] = pk2((lo-mean)*rstd*sc[2*j] + bi[2*j], (hi-mean)*rstd*sc[2*j+1] + bi[2*j+1]);
  }
  *(u32x4*)(hn + i) = o;
}

__global__ __launch_bounds__(256) void k_wtrans4(const float* __restrict__ wq, const float* __restrict__ wk,
    const float* __restrict__ wv, const float* __restrict__ wo,
    u16* __restrict__ wqkvT, u16* __restrict__ woT){
  int j = blockIdx.x*256 + threadIdx.x;
  int wsel = j >> 18, r = j & 262143;
  int n = r >> 9, k = r & 511;
  const float* src = wsel==0?wq : wsel==1?wk : wsel==2?wv : wo;
  u16 v = f2bf(src[k*512 + n]);
  if (wsel < 3) wqkvT[(size_t)wsel*262144 + r] = v;
  else          woT[r] = v;
}

__global__ __launch_bounds__(256) void k_sumred(const float* __restrict__ part, float* __restrict__ sums){
  int row = blockIdx.x*4 + (threadIdx.x >> 6);
  int l = threadIdx.x & 63;
  float s = part[(size_t)row*64 + l];
  #pragma unroll
  for (int o = 32; o; o >>= 1) s += __shfl_xor(s, o);
  if (l == 0) sums[row] = s;
}

__global__ __launch_bounds__(256) void k_pvred(const u16* __restrict__ op, const float* __restrict__ sums,
    u16* __restrict__ o){
  size_t i = ((size_t)blockIdx.x*256 + threadIdx.x)*8;
  int row = (int)(i >> 9);
  float inv = 1.f/sums[row];
  u32x4 a = __builtin_nontemporal_load((const u32x4*)(op + i));
  u32x4 b = __builtin_nontemporal_load((const u32x4*)(op + (size_t)NM*NC + i));
  uint32_t r[4];
  #pragma unroll
  for (int j=0;j<4;j++){
    float lo = (bfu(a[j] & 0xFFFFu) + bfu(b[j] & 0xFFFFu)) * inv;
    float hi = (__builtin_bit_cast(float, a[j] & 0xFFFF0000u) +
                __builtin_bit_cast(float, b[j] & 0xFFFF0000u)) * inv;
    r[j] = (uint32_t)f2bf(lo) | ((uint32_t)f2bf(hi) << 16);
  }
  *(uint4*)(o + i) = make_uint4(r[0], r[1], r[2], r[3]);
}

// ============ bf16 16B-granule swizzle machinery (QKV / out-proj) ============
#define NTQ 16   // K=512 / BK=32 (bf16 kernels)

__device__ __forceinline__ int dec_rl(int L, int p){ return 2*L + ((p>>2) ^ ((L>>1)&1)); }
__device__ __forceinline__ int dec_kq(int L, int p){
  int P01 = ((((L)&1)^((L>>2)&1))<<1) | (((L>>1)&1)^((L>>3)&1));
  return (p&3) ^ P01;
}
__device__ __forceinline__ int swz_off(int rl, int kq){
  int Pq = (((rl&1)^((rl>>2)&1))<<2) | ((((rl>>1)&1)^((rl>>3)&1))<<1) | (((rl>>2)&1)^((rl>>4)&1));
  return ((rl>>1)<<7) + ((Pq ^ kq)<<4);
}

// ====== k_qkv: QKV projection — 128x256 tile, 8 waves, BK=32, ring-3, 2 blocks/CU ======
__global__ __launch_bounds__(512, 4) void k_qkv(
    const u16* __restrict__ A, const u16* __restrict__ B,
    uint8_t* __restrict__ q8, uint8_t* __restrict__ k8, uint8_t* __restrict__ v8T,
    const float* __restrict__ bias0, const float* __restrict__ bias1, const float* __restrict__ bias2)
{
  __shared__ u16 LDS[36864];   // 72 KiB: B 3x16KB @0, A 3x8KB @49152
  char* Lb = (char*)LDS;
  const int t = threadIdx.x;
  const int l = t & 63, w = t >> 6;
  const int wr = w >> 2, wc = w & 3;
  const int frow = l & 15, kq = l >> 4;
  const int nx = gridDim.x, ny = gridDim.y;
  int f = (int)blockIdx.y*nx + (int)blockIdx.x;
  const int nwg = nx*ny;
  f = (f & 7)*(nwg >> 3) + (f >> 3);
  const int bx = f % nx; const int by = f / nx;
  const int brow = by*128, bcol = bx*256;

  const int pA = t & 7;
  const int LA = t >> 3;
  const int LB0 = t >> 3, LB1 = 64 + (t >> 3);
  const int rlA  = dec_rl(LA, pA),  kqA  = dec_kq(LA, pA);
  const int rlB0 = dec_rl(LB0, pA), kqB0 = dec_kq(LB0, pA);
  const int rlB1 = dec_rl(LB1, pA), kqB1 = dec_kq(LB1, pA);
  const u16* Ap  = A + (size_t)(brow + rlA )*NC + kqA*8;
  const u16* Bp0 = B + (size_t)(bcol + rlB0)*NC + kqB0*8;
  const u16* Bp1 = B + (size_t)(bcol + rlB1)*NC + kqB1*8;

  auto stage = [&](int buf, int kt){
    const size_t ko = (size_t)kt*32;
    gll16(Bp0 + ko, Lb + buf*16384 + t*16);
    gll16(Bp1 + ko, Lb + buf*16384 + 8192 + t*16);
    gll16(Ap  + ko, Lb + 49152 + buf*8192 + t*16);
  };

  int offA[4], offB[4];
  #pragma unroll
  for (int m=0;m<4;m++) offA[m] = swz_off(wr*64 + m*16 + frow, kq);
  #pragma unroll
  for (int c=0;c<4;c++) offB[c] = swz_off(wc*64 + 4*frow + c, kq);

  f32x4 acc[4][4] = {};

  auto body = [&](int buf, int s){
    bf16x8 a4[4], b4[4];
    #pragma unroll
    for (int m=0;m<4;m++) a4[m] = *(const bf16x8*)(Lb + 49152 + buf*8192 + offA[m]);
    #pragma unroll
    for (int c=0;c<4;c++) b4[c] = *(const bf16x8*)(Lb + buf*16384 + offB[c]);
    const bool doStage = (s + 2 < NTQ);
    if (doStage){ int nb = buf+2; if (nb>=3) nb-=3; stage(nb, s+2); }
    asm volatile("s_waitcnt lgkmcnt(0)" ::: "memory");
    __builtin_amdgcn_sched_barrier(0);
    __builtin_amdgcn_s_setprio(1);
    #pragma unroll
    for (int m=0;m<4;m++)
      #pragma unroll
      for (int c=0;c<4;c++)
        acc[m][c] = MFMA_(a4[m], b4[c], acc[m][c]);
    __builtin_amdgcn_s_setprio(0);
    __builtin_amdgcn_sched_barrier(0);
    if (s + 1 < NTQ){
      if (doStage) asm volatile("s_waitcnt vmcnt(3)" ::: "memory");
      else         asm volatile("s_waitcnt vmcnt(0)" ::: "memory");
      __builtin_amdgcn_s_barrier();
    }
  };

  stage(0, 0); stage(1, 1);
  asm volatile("s_waitcnt vmcnt(3)" ::: "memory");
  __builtin_amdgcn_s_barrier();

  #pragma unroll
  for (int i = 0; i < 5; i++){
    body(0, i*3);
    body(1, i*3+1);
    body(2, i*3+2);
  }
  body(0, 15);

  const int col4 = wc*64 + 4*frow;
  const int seg = bcol >> 9;
  const int colr = (bcol & 511) + col4;
  if (seg < 2){
    uint8_t* dq = seg==0 ? q8 : k8;
    const float* bp = seg==0 ? bias0 : bias1;
    const float4 bi = *(const float4*)(bp + colr);
    #pragma unroll
    for (int m=0;m<4;m++){
      #pragma unroll
      for (int r=0;r<4;r++){
        const int rr = brow + wr*64 + m*16 + kq*4 + r;
        unsigned int pv = __builtin_amdgcn_cvt_pk_fp8_f32(acc[m][0][r]+bi.x, acc[m][1][r]+bi.y, 0u, false);
        pv = __builtin_amdgcn_cvt_pk_fp8_f32(acc[m][2][r]+bi.z, acc[m][3][r]+bi.w, pv, true);
        *(unsigned int*)&dq[(size_t)rr*NC + colr] = pv;
      }
    }
  } else {
    const float4 bi = *(const float4*)(bias2 + colr);
    const float bvs[4] = {bi.x, bi.y, bi.z, bi.w};
    #pragma unroll
    for (int m=0;m<4;m++){
      const int rr0 = brow + wr*64 + m*16 + kq*4;
      const int b = rr0 >> 12, sq = rr0 & 4095;
      #pragma unroll
      for (int n=0;n<4;n++){
        unsigned int pv = __builtin_amdgcn_cvt_pk_fp8_f32(acc[m][n][0]+bvs[n], acc[m][n][1]+bvs[n], 0u, false);
        pv = __builtin_amdgcn_cvt_pk_fp8_f32(acc[m][n][2]+bvs[n], acc[m][n][3]+bvs[n], pv, true);
        *(unsigned int*)&v8T[((size_t)(b*NC + colr + n) << 12) + sq] = pv;
      }
    }
  }
}

// ====== fp8 8B-granule machinery (pv8) ======
__device__ __forceinline__ int rdoff8(int rl, int ks){
  int slot8 = ((rl&1)<<3) | (((((ks>>1) ^ (rl>>1)) & 3))<<1) | (ks&1);
  return ((rl>>1)<<7) + (slot8<<3);
}
__device__ __forceinline__ int cmap64(int p){
  return (p & 192) + (((p & 15) << 2) | ((p >> 4) & 3));
}

// ====== k_qk8 (MX): FP8 QK^T via mfma_scale 32x32x64, unit scales ======
// 128x256 tile, 8 waves (2x4) of 64x64 (2x2 32x32 frags), BK=64B, ring-3 72KB,
// 2 blocks/CU. Lane reads 32B contiguous at rl*64 + (l>>5)*32 -> bank-floor,
// LINEAR LDS + LINEAR gll16 sources (no swizzle needed at 32B granularity).
__global__ __launch_bounds__(512, 4) void k_qk8(
    const uint8_t* __restrict__ Q8, const uint8_t* __restrict__ K8,
    uint8_t* __restrict__ P8, float* __restrict__ partsum, float alpha)
{
  __shared__ char LDS[73728];
  char* LA = LDS;            // 3 x 8192
  char* LB = LDS + 24576;    // 3 x 16384
  const int t = threadIdx.x;
  const int l = t & 63, w = t >> 6;
  const int wr = w >> 2, wc = w & 3;
  const int l31 = l & 31, kh = l >> 5;
  int f = ((int)blockIdx.z*32 + (int)blockIdx.y)*16 + (int)blockIdx.x;
  f = (f & 7)*256 + (f >> 3);
  const int bx = f & 15; const int t2 = f >> 4;
  const int by = t2 & 31; const int bb = t2 >> 5;
  const int brow = by*128, bcol = bx*256;
  const size_t bOff = (size_t)bb*NSEQ*NC;

  // linear staging: thread t covers row t>>2, 16B slot t&3
  const uint8_t* Ap  = Q8 + bOff + (size_t)(brow + (t>>2))*NC + (t&3)*16;
  const uint8_t* Bp0 = K8 + bOff + (size_t)(bcol + (t>>2))*NC + (t&3)*16;
  const uint8_t* Bp1 = K8 + bOff + (size_t)(bcol + 128 + (t>>2))*NC + (t&3)*16;

  auto stage = [&](int buf, int kt){
    const size_t ko = (size_t)kt*64;
    gll16(Ap  + ko, LA + buf*8192 + t*16);
    gll16(Bp0 + ko, LB + buf*16384 + t*16);
    gll16(Bp1 + ko, LB + buf*16384 + 8192 + t*16);
  };

  int offA[2], offB[2];
  #pragma unroll
  for (int mi=0;mi<2;mi++) offA[mi] = (wr*64 + mi*32 + l31)*64 + kh*32;
  #pragma unroll
  for (int ni=0;ni<2;ni++) offB[ni] = (wc*64 + ni*32 + l31)*64 + kh*32;

  f32x16 acc[2][2] = {};

  auto body = [&](int buf, int s){
    v8i a0 = *(const v8i*)(LA + buf*8192  + offA[0]);
    v8i a1 = *(const v8i*)(LA + buf*8192  + offA[1]);
    v8i b0 = *(const v8i*)(LB + buf*16384 + offB[0]);
    v8i b1 = *(const v8i*)(LB + buf*16384 + offB[1]);
    const bool doStage = (s + 2 < 8);
    if (doStage){ int nb = buf+2; if (nb>=3) nb-=3; stage(nb, s+2); }
    asm volatile("s_waitcnt lgkmcnt(0)" ::: "memory");
    __builtin_amdgcn_sched_barrier(0);
    __builtin_amdgcn_s_setprio(1);
    acc[0][0] = MFMAX_(a0, b0, acc[0][0]);
    acc[0][1] = MFMAX_(a0, b1, acc[0][1]);
    acc[1][0] = MFMAX_(a1, b0, acc[1][0]);
    acc[1][1] = MFMAX_(a1, b1, acc[1][1]);
    __builtin_amdgcn_s_setprio(0);
    __builtin_amdgcn_sched_barrier(0);
    if (s + 1 < 8){
      if (doStage) asm volatile("s_waitcnt vmcnt(3)" ::: "memory");
      else         asm volatile("s_waitcnt vmcnt(0)" ::: "memory");
      __builtin_amdgcn_s_barrier();
    }
  };

  stage(0, 0); stage(1, 1);
  asm volatile("s_waitcnt vmcnt(3)" ::: "memory");
  __builtin_amdgcn_s_barrier();

  body(0,0); body(1,1); body(2,2); body(0,3);
  body(1,4); body(2,5); body(0,6); body(1,7);

  // epilogue: exp -> fp8 P (scalar byte stores, 32B-coalesced runs) + row partials
  // C/D layout (m74/m101): col = l&31, row = (reg&3) + 8*(reg>>2) + 4*(l>>5)
  uint8_t* Pp = P8 + (size_t)bb*NSEQ*NSEQ;
  const int colg = bcol + wc*64 + l31;
  #pragma unroll
  for (int mi=0; mi<2; mi++){
    #pragma unroll
    for (int reg=0; reg<16; reg++){
      const int rr = brow + wr*64 + mi*32 + (reg&3) + 8*(reg>>2) + 4*kh;
      float e0 = __expf(alpha*acc[mi][0][reg]);
      float e1 = __expf(alpha*acc[mi][1][reg]);
      unsigned int c0 = __builtin_amdgcn_cvt_pk_fp8_f32(e0, e0, 0u, false);
      unsigned int c1 = __builtin_amdgcn_cvt_pk_fp8_f32(e1, e1, 0u, false);
      Pp[(size_t)rr*NSEQ + colg]      = (uint8_t)(c0 & 0xFF);
      Pp[(size_t)rr*NSEQ + colg + 32] = (uint8_t)(c1 & 0xFF);
      float rs = e0 + e1;
      rs += __shfl_xor(rs, 1); rs += __shfl_xor(rs, 2);
      rs += __shfl_xor(rs, 4); rs += __shfl_xor(rs, 8);
      rs += __shfl_xor(rs, 16);
      if (l31 == 0)
        partsum[((size_t)bb*NSEQ + rr)*64 + bx*4 + wc] = rs;
    }
  }
}

// ====== k_pv8: FP8 PV split-K — 128x256, BK=64B, ring-3, 2 blocks/CU (unchanged) ======
__global__ __launch_bounds__(512, 4) void k_pv8(
    const uint8_t* __restrict__ P8, const uint8_t* __restrict__ V8,
    u16* __restrict__ opart)
{
  __shared__ char LDS[73728];
  char* LA = LDS;
  char* LB = LDS + 24576;
  const int t = threadIdx.x;
  const int l = t & 63, w = t >> 6;
  const int wr = w >> 2, wc = w & 3;
  const int frow = l & 15, kq = l >> 4;
  int f = ((int)blockIdx.z*32 + (int)blockIdx.y)*2 + (int)blockIdx.x;
  f = (f & 7)*64 + (f >> 3);
  const int bx = f & 1; const int t2 = f >> 1;
  const int by = t2 & 31; const int bz = t2 >> 5;
  const int bb = bz & 3; const int sp = bz >> 2;
  const int brow = by*128, bcol = bx*256;
  const int kOff = sp*(NSEQ/2);

  const int Lp = t >> 3, p2 = t & 7;
  const int rlu = 2*Lp + (p2 >> 2);
  const int gru = (p2 & 3) ^ (Lp & 3);
  const uint8_t* Ap  = P8 + (size_t)bb*NSEQ*NSEQ + (size_t)(brow + rlu)*NSEQ + kOff + gru*16;
  const uint8_t* Bp0 = V8 + (size_t)bb*NC*NSEQ + (size_t)(bcol + cmap64(rlu))*NSEQ + kOff + gru*16;
  const uint8_t* Bp1 = V8 + (size_t)bb*NC*NSEQ + (size_t)(bcol + cmap64(rlu + 128))*NSEQ + kOff + gru*16;

  auto stage = [&](int buf, int kt){
    const size_t ko = (size_t)kt*64;
    gll16(Ap  + ko, LA + buf*8192 + t*16);
    gll16(Bp0 + ko, LB + buf*16384 + t*16);
    gll16(Bp1 + ko, LB + buf*16384 + 8192 + t*16);
  };

  int offA[4], offB[4];
  #pragma unroll
  for (int m=0;m<4;m++) offA[m] = rdoff8(wr*64 + m*16 + frow, kq);
  #pragma unroll
  for (int n=0;n<4;n++) offB[n] = rdoff8(wc*64 + n*16 + frow, kq);

  f32x4 acc[4][4] = {};

  auto body = [&](int buf, int s){
    i64 a0[4], a1[4], b0[4], b1[4];
    const char* Ab = LA + buf*8192;
    const char* Bb = LB + buf*16384;
    #pragma unroll
    for (int m=0;m<4;m++){ a0[m] = *(const i64*)(Ab + offA[m]); a1[m] = *(const i64*)(Ab + (offA[m]^32)); }
    #pragma unroll
    for (int n=0;n<4;n++){ b0[n] = *(const i64*)(Bb + offB[n]); b1[n] = *(const i64*)(Bb + (offB[n]^32)); }
    const bool doStage = (s + 2 < 32);
    if (doStage){ int nb = buf+2; if (nb>=3) nb-=3; stage(nb, s+2); }
    asm volatile("s_waitcnt lgkmcnt(0)" ::: "memory");
    __builtin_amdgcn_sched_barrier(0);
    __builtin_amdgcn_s_setprio(1);
    #pragma unroll
    for (int m=0;m<4;m++)
      #pragma unroll
      for (int n=0;n<4;n++){
        acc[m][n] = MFMA8_(a0[m], b0[n], acc[m][n]);
        acc[m][n] = MFMA8_(a1[m], b1[n], acc[m][n]);
      }
    __builtin_amdgcn_s_setprio(0);
    __builtin_amdgcn_sched_barrier(0);
    if (s + 1 < 32){
      if (doStage) asm volatile("s_waitcnt vmcnt(3)" ::: "memory");
      else         asm volatile("s_waitcnt vmcnt(0)" ::: "memory");
      __builtin_amdgcn_s_barrier();
    }
  };

  stage(0, 0); stage(1, 1);
  asm volatile("s_waitcnt vmcnt(3)" ::: "memory");
  __builtin_amdgcn_s_barrier();

  #pragma unroll
  for (int i = 0; i < 10; i++){
    body(0, i*3);
    body(1, i*3+1);
    body(2, i*3+2);
  }
  body(0, 30); body(1, 31);

  u16* op = opart + (size_t)sp*NM*NC + (size_t)bb*NSEQ*NC;
  const int col4 = bcol + wc*64 + 4*frow;
  #pragma unroll
  for (int m=0;m<4;m++){
    #pragma unroll
    for (int r=0;r<4;r++){
      const int rr = brow + wr*64 + m*16 + kq*4 + r;
      u32x2 wv;
      wv[0] = pk2(acc[m][0][r], acc[m][1][r]);
      wv[1] = pk2(acc[m][2][r], acc[m][3][r]);
      __builtin_nontemporal_store(wv, (u32x2*)&op[(size_t)rr*NC + col4]);
    }
  }
}

// ====== k_t256o: out-projection — 128x128 tile, 4 waves, BK=32, ring-3, 48KB ======
__global__ __launch_bounds__(256, 3) void k_t256o(
    const u16* __restrict__ A, const u16* __restrict__ B,
    float* __restrict__ out, const float* __restrict__ bias, const float* __restrict__ res)
{
  __shared__ u16 LDS[24576];
  char* Lb = (char*)LDS;
  const int t = threadIdx.x;
  const int l = t & 63, w = t >> 6;
  const int wr = w >> 1, wc = w & 1;
  const int frow = l & 15, kq = l >> 4;
  int f = (int)blockIdx.y*4 + (int)blockIdx.x;
  f = (f & 7)*64 + (f >> 3);
  const int bx = f & 3; const int by = f >> 2;
  const int brow = by*128, bcol = bx*128;

  const int pA = t & 7;
  const int L0 = t >> 3;
  const int rl0 = dec_rl(L0, pA),      kq0 = dec_kq(L0, pA);
  const int rl1 = dec_rl(L0+32, pA),   kq1 = dec_kq(L0+32, pA);
  const u16* Ap0 = A + (size_t)(brow + rl0)*NC + kq0*8;
  const u16* Ap1 = A + (size_t)(brow + rl1)*NC + kq1*8;
  const u16* Bp0 = B + (size_t)(bcol + rl0)*NC + kq0*8;
  const u16* Bp1 = B + (size_t)(bcol + rl1)*NC + kq1*8;

  auto stage = [&](int buf, int kt){
    const size_t ko = (size_t)kt*32;
    gll16(Ap0 + ko, Lb + buf*16384 + t*16);
    gll16(Ap1 + ko, Lb + buf*16384 + 4096 + t*16);
    gll16(Bp0 + ko, Lb + buf*16384 + 8192 + t*16);
    gll16(Bp1 + ko, Lb + buf*16384 + 12288 + t*16);
  };

  int offA[4], offB[4];
  #pragma unroll
  for (int m=0;m<4;m++) offA[m] = swz_off(wr*64 + m*16 + frow, kq);
  #pragma unroll
  for (int c=0;c<4;c++) offB[c] = swz_off(wc*64 + 4*frow + c, kq);

  f32x4 acc[4][4] = {};

  auto body = [&](int buf, int s){
    bf16x8 a4[4], b4[4];
    #pragma unroll
    for (int m=0;m<4;m++) a4[m] = *(const bf16x8*)(Lb + buf*16384 + offA[m]);
    #pragma unroll
    for (int c=0;c<4;c++) b4[c] = *(const bf16x8*)(Lb + buf*16384 + 8192 + offB[c]);
    const bool doStage = (s + 2 < NTQ);
    if (doStage){ int nb = buf+2; if (nb>=3) nb-=3; stage(nb, s+2); }
    asm volatile("s_waitcnt lgkmcnt(0)" ::: "memory");
    __builtin_amdgcn_sched_barrier(0);
    __builtin_amdgcn_s_setprio(1);
    #pragma unroll
    for (int m=0;m<4;m++)
      #pragma unroll
      for (int c=0;c<4;c++)
        acc[m][c] = MFMA_(a4[m], b4[c], acc[m][c]);
    __builtin_amdgcn_s_setprio(0);
    __builtin_amdgcn_sched_barrier(0);
    if (s + 1 < NTQ){
      if (doStage) asm volatile("s_waitcnt vmcnt(4)" ::: "memory");
      else         asm volatile("s_waitcnt vmcnt(0)" ::: "memory");
      __builtin_amdgcn_s_barrier();
    }
  };

  stage(0, 0); stage(1, 1);
  asm volatile("s_waitcnt vmcnt(4)" ::: "memory");
  __builtin_amdgcn_s_barrier();

  #pragma unroll
  for (int i = 0; i < 5; i++){
    body(0, i*3);
    body(1, i*3+1);
    body(2, i*3+2);
  }
  body(0, 15);

  const int c = bcol + wc*64 + 4*frow;
  const float4 bi = *(const float4*)(bias + c);
  #pragma unroll
  for (int m=0;m<4;m++){
    #pragma unroll
    for (int r=0;r<4;r++){
      const int rr = brow + wr*64 + m*16 + kq*4 + r;
      const float4 rv = *(const float4*)(res + (size_t)rr*NC + c);
      float4 ov;
      ov.x = acc[m][0][r] + bi.x + rv.x;
      ov.y = acc[m][1][r] + bi.y + rv.y;
      ov.z = acc[m][2][r] + bi.z + rv.z;
      ov.w = acc[m][3][r] + bi.w + rv.w;
      *(float4*)&out[(size_t)rr*NC + c] = ov;
    }
  }
}

extern "C" void kernel_launch(void* const* d_in, const int* in_sizes, int n_in,
                              void* d_out, int out_size, void* d_ws, size_t ws_size,
                              hipStream_t stream){
  const float* x   = (const float*)d_in[0];
  const float* gsc = (const float*)d_in[1];
  const float* gbi = (const float*)d_in[2];
  const float* wq  = (const float*)d_in[3];
  const float* bq  = (const float*)d_in[4];
  const float* wk  = (const float*)d_in[5];
  const float* bk  = (const float*)d_in[6];
  const float* wv  = (const float*)d_in[7];
  const float* bv  = (const float*)d_in[8];
  const float* wo  = (const float*)d_in[9];
  const float* bo  = (const float*)d_in[10];
  float* out = (float*)d_out;

  char* wsp = (char*)d_ws;
  size_t off = 0;
  auto alloc = [&](size_t bytes)->void*{ void* p = wsp + off; off += (bytes + 255) & ~(size_t)255; return p; };
  float* stats   = (float*)alloc((size_t)NB*NG*2*sizeof(float));
  float* sums    = (float*)alloc((size_t)NM*sizeof(float));
  float* partsum = (float*)alloc((size_t)NM*64*sizeof(float));
  u16* xbf   = (u16*)alloc((size_t)NM*NC*2);   // dead after gn_apply2
  u16* hn    = (u16*)alloc((size_t)NM*NC*2);   // dead after k_qkv
  u16* wqkvT = (u16*)alloc((size_t)3*NC*NC*2);
  u16* woT   = (u16*)alloc((size_t)NC*NC*2);
  uint8_t* q8 = (uint8_t*)alloc((size_t)NM*NC);
  uint8_t* k8 = (uint8_t*)alloc((size_t)NM*NC);
  uint8_t* v8 = (uint8_t*)alloc((size_t)NM*NC);
  u16* o     = (u16*)alloc((size_t)NM*NC*2);
  uint8_t* P8 = (uint8_t*)alloc((size_t)NB*NSEQ*NSEQ);
  u16* opart = xbf;  // PV split-K partials [2][NM][NC] alias xbf+hn (32 MiB, both dead)

  k_zero<<<1,256,0,stream>>>(stats, NB*NG*2);
  k_gn_stats2<<<NB*64,256,0,stream>>>(x, xbf, stats);
  k_gn_apply2<<<4096,256,0,stream>>>(xbf, stats, gsc, gbi, hn);
  k_wtrans4<<<4096,256,0,stream>>>(wq, wk, wv, wo, wqkvT, woT);

  // QKV projection: q,k,v all fp8 out
  k_qkv<<<dim3(6,128,1),512,0,stream>>>(hn, wqkvT, q8, k8, v8, bq, bk, bv);

  const float scale = 0.044194173824159216f;  // 512^-0.5
  // QK^T fp8 via MX-scaled 32x32x64 (unit scales) -> fp8 P + row partials
  k_qk8<<<dim3(16,32,NB),512,0,stream>>>(q8, k8, P8, partsum, scale);
  k_sumred<<<NM/4,256,0,stream>>>(partsum, sums);
  // PV fp8 split-K=2 (unchanged)
  k_pv8<<<dim3(2,32,8),512,0,stream>>>(P8, v8, opart);
  k_pvred<<<NM*NC/8/256,256,0,stream>>>(opart, sums, o);
  // output projection + bias + residual
  k_t256o<<<dim3(4,128,1),256,0,stream>>>(o, woT, out, bo, x);
}

// Round 13
// 323.322 us; speedup vs baseline: 1.3142x; 1.3142x over previous
//
#include <hip/hip_runtime.h>
#include <stdint.h>

typedef unsigned short u16;
typedef long i64;
typedef __bf16 bf16x8 __attribute__((ext_vector_type(8)));
typedef float f32x4 __attribute__((ext_vector_type(4)));
typedef float f32x16 __attribute__((ext_vector_type(16)));
typedef int v8i __attribute__((ext_vector_type(8)));
typedef uint32_t u32x2 __attribute__((ext_vector_type(2)));
typedef uint32_t u32x4 __attribute__((ext_vector_type(4)));

#define NB 4
#define NC 512
#define NG 32
#define NSEQ 4096
#define NM (NB*NSEQ)

#define MFMA_(a,b,c) __builtin_amdgcn_mfma_f32_16x16x32_bf16(a,b,c,0,0,0)
#define MFMA8_(a,b,c) __builtin_amdgcn_mfma_f32_16x16x32_fp8_fp8(a,b,c,0,0,0)
// MX-scaled 32x32x64 fp8xfp8, unit scales (e8m0 127 = 1.0): numerics identical
#define MFMAX_(a,b,c) __builtin_amdgcn_mfma_scale_f32_32x32x64_f8f6f4(a,b,c,0,0,0,127,0,127)

__device__ __forceinline__ u16 f2bf(float f){
  uint32_t u = __builtin_bit_cast(uint32_t, f);
  u += 0x7FFFu + ((u >> 16) & 1u);
  return (u16)(u >> 16);
}
__device__ __forceinline__ float bfu(uint32_t lo16){
  return __builtin_bit_cast(float, lo16 << 16);
}
__device__ __forceinline__ uint32_t pk2(float a, float b){
  return (uint32_t)f2bf(a) | ((uint32_t)f2bf(b) << 16);
}

__device__ __forceinline__ void gll16(const void* g, void* l){
  __builtin_amdgcn_global_load_lds(
      (const __attribute__((address_space(1))) void*)g,
      (__attribute__((address_space(3))) void*)l, 16, 0, 0);
}

__global__ void k_zero(float* p, int n){
  int i = blockIdx.x*blockDim.x + threadIdx.x;
  if (i < n) p[i] = 0.f;
}

// GN pass 1: row-major read of x, per-group partial sums + bf16 copy of x.
__global__ __launch_bounds__(256) void k_gn_stats2(const float* __restrict__ x,
    u16* __restrict__ xbf, float* __restrict__ stats){
  int blk = blockIdx.x;
  int b = blk >> 6, ch = blk & 63;
  int t = threadIdx.x;
  int colv = t & 127;
  int r0 = ch*64 + (t >> 7);
  const float* xp = x  + (size_t)b*NSEQ*NC + (size_t)r0*NC + colv*4;
  u16* xb       = xbf + (size_t)b*NSEQ*NC + (size_t)r0*NC + colv*4;
  float s1 = 0.f, s2 = 0.f;
  #pragma unroll 4
  for (int i = 0; i < 32; i++){
    float4 v = *(const float4*)(xp + (size_t)i*2*NC);
    s1 += v.x+v.y+v.z+v.w;
    s2 += v.x*v.x+v.y*v.y+v.z*v.z+v.w*v.w;
    ushort4 o; o.x=f2bf(v.x); o.y=f2bf(v.y); o.z=f2bf(v.z); o.w=f2bf(v.w);
    *(ushort4*)(xb + (size_t)i*2*NC) = o;
  }
  s1 += __shfl_xor(s1,1); s2 += __shfl_xor(s2,1);
  s1 += __shfl_xor(s1,2); s2 += __shfl_xor(s2,2);
  __shared__ float ls1[4][16], ls2[4][16];
  int w = t >> 6, l = t & 63;
  if ((l & 3) == 0){ ls1[w][l>>2] = s1; ls2[w][l>>2] = s2; }
  __syncthreads();
  if (t < 32){
    int g = t;
    int wlo = g >> 4;
    float a1 = ls1[wlo][g&15] + ls1[wlo+2][g&15];
    float a2 = ls2[wlo][g&15] + ls2[wlo+2][g&15];
    atomicAdd(&stats[(b*NG+g)*2+0], a1);
    atomicAdd(&stats[(b*NG+g)*2+1], a2);
  }
}

// GN pass 2: read bf16 x-copy, normalize+affine, write hn.
__global__ __launch_bounds__(256) void k_gn_apply2(const u16* __restrict__ xbf,
    const float* __restrict__ stats, const float* __restrict__ gsc,
    const float* __restrict__ gbi, u16* __restrict__ hn){
  const float inv_cnt = 1.f/((float)NSEQ*16.f);
  size_t i = ((size_t)blockIdx.x*256 + threadIdx.x)*8;
  int c = (int)(i & 511);
  int b = (int)(i >> 21);
  int g = c >> 4;
  float s1 = stats[(b*NG+g)*2], s2 = stats[(b*NG+g)*2+1];
  float mean = s1*inv_cnt;
  float rstd = rsqrtf(s2*inv_cnt - mean*mean + 1e-6f);
  u32x4 v = *(const u32x4*)(xbf + i);
  float4 scA = *(const float4*)(gsc + c), scB = *(const float4*)(gsc + c + 4);
  float4 biA = *(const float4*)(gbi + c), biB = *(const float4*)(gbi + c + 4);
  const float sc[8] = {scA.x,scA.y,scA.z,scA.w,scB.x,scB.y,scB.z,scB.w};
  const float bi[8] = {biA.x,biA.y,biA.z,biA.w,biB.x,biB.y,biB.z,biB.w};
  u32x4 o;
  #pragma unroll
  for (int j = 0; j < 4; j++){
    float lo = bfu(v[j] & 0xFFFFu);
    float hi = __builtin_bit_cast(float, v[j] & 0xFFFF0000u);
    o[j] = pk2((lo-mean)*rstd*sc[2*j] + bi[2*j], (hi-mean)*rstd*sc[2*j+1] + bi[2*j+1]);
  }
  *(u32x4*)(hn + i) = o;
}

__global__ __launch_bounds__(256) void k_wtrans4(const float* __restrict__ wq, const float* __restrict__ wk,
    const float* __restrict__ wv, const float* __restrict__ wo,
    u16* __restrict__ wqkvT, u16* __restrict__ woT){
  int j = blockIdx.x*256 + threadIdx.x;
  int wsel = j >> 18, r = j & 262143;
  int n = r >> 9, k = r & 511;
  const float* src = wsel==0?wq : wsel==1?wk : wsel==2?wv : wo;
  u16 v = f2bf(src[k*512 + n]);
  if (wsel < 3) wqkvT[(size_t)wsel*262144 + r] = v;
  else          woT[r] = v;
}

__global__ __launch_bounds__(256) void k_sumred(const float* __restrict__ part, float* __restrict__ sums){
  int row = blockIdx.x*4 + (threadIdx.x >> 6);
  int l = threadIdx.x & 63;
  float s = part[(size_t)row*64 + l];
  #pragma unroll
  for (int o = 32; o; o >>= 1) s += __shfl_xor(s, o);
  if (l == 0) sums[row] = s;
}

__global__ __launch_bounds__(256) void k_pvred(const u16* __restrict__ op, const float* __restrict__ sums,
    u16* __restrict__ o){
  size_t i = ((size_t)blockIdx.x*256 + threadIdx.x)*8;
  int row = (int)(i >> 9);
  float inv = 1.f/sums[row];
  u32x4 a = __builtin_nontemporal_load((const u32x4*)(op + i));
  u32x4 b = __builtin_nontemporal_load((const u32x4*)(op + (size_t)NM*NC + i));
  uint32_t r[4];
  #pragma unroll
  for (int j=0;j<4;j++){
    float lo = (bfu(a[j] & 0xFFFFu) + bfu(b[j] & 0xFFFFu)) * inv;
    float hi = (__builtin_bit_cast(float, a[j] & 0xFFFF0000u) +
                __builtin_bit_cast(float, b[j] & 0xFFFF0000u)) * inv;
    r[j] = (uint32_t)f2bf(lo) | ((uint32_t)f2bf(hi) << 16);
  }
  *(uint4*)(o + i) = make_uint4(r[0], r[1], r[2], r[3]);
}

// ============ bf16 16B-granule swizzle machinery (QKV / out-proj) ============
#define NTQ 16   // K=512 / BK=32 (bf16 kernels)

__device__ __forceinline__ int dec_rl(int L, int p){ return 2*L + ((p>>2) ^ ((L>>1)&1)); }
__device__ __forceinline__ int dec_kq(int L, int p){
  int P01 = ((((L)&1)^((L>>2)&1))<<1) | (((L>>1)&1)^((L>>3)&1));
  return (p&3) ^ P01;
}
__device__ __forceinline__ int swz_off(int rl, int kq){
  int Pq = (((rl&1)^((rl>>2)&1))<<2) | ((((rl>>1)&1)^((rl>>3)&1))<<1) | (((rl>>2)&1)^((rl>>4)&1));
  return ((rl>>1)<<7) + ((Pq ^ kq)<<4);
}

// ====== k_qkv: QKV projection — 128x256 tile, 8 waves, BK=32, ring-3, 2 blocks/CU ======
__global__ __launch_bounds__(512, 4) void k_qkv(
    const u16* __restrict__ A, const u16* __restrict__ B,
    uint8_t* __restrict__ q8, uint8_t* __restrict__ k8, uint8_t* __restrict__ v8T,
    const float* __restrict__ bias0, const float* __restrict__ bias1, const float* __restrict__ bias2)
{
  __shared__ u16 LDS[36864];   // 72 KiB: B 3x16KB @0, A 3x8KB @49152
  char* Lb = (char*)LDS;
  const int t = threadIdx.x;
  const int l = t & 63, w = t >> 6;
  const int wr = w >> 2, wc = w & 3;
  const int frow = l & 15, kq = l >> 4;
  const int nx = gridDim.x, ny = gridDim.y;
  int f = (int)blockIdx.y*nx + (int)blockIdx.x;
  const int nwg = nx*ny;
  f = (f & 7)*(nwg >> 3) + (f >> 3);
  const int bx = f % nx; const int by = f / nx;
  const int brow = by*128, bcol = bx*256;

  const int pA = t & 7;
  const int LA = t >> 3;
  const int LB0 = t >> 3, LB1 = 64 + (t >> 3);
  const int rlA  = dec_rl(LA, pA),  kqA  = dec_kq(LA, pA);
  const int rlB0 = dec_rl(LB0, pA), kqB0 = dec_kq(LB0, pA);
  const int rlB1 = dec_rl(LB1, pA), kqB1 = dec_kq(LB1, pA);
  const u16* Ap  = A + (size_t)(brow + rlA )*NC + kqA*8;
  const u16* Bp0 = B + (size_t)(bcol + rlB0)*NC + kqB0*8;
  const u16* Bp1 = B + (size_t)(bcol + rlB1)*NC + kqB1*8;

  auto stage = [&](int buf, int kt){
    const size_t ko = (size_t)kt*32;
    gll16(Bp0 + ko, Lb + buf*16384 + t*16);
    gll16(Bp1 + ko, Lb + buf*16384 + 8192 + t*16);
    gll16(Ap  + ko, Lb + 49152 + buf*8192 + t*16);
  };

  int offA[4], offB[4];
  #pragma unroll
  for (int m=0;m<4;m++) offA[m] = swz_off(wr*64 + m*16 + frow, kq);
  #pragma unroll
  for (int c=0;c<4;c++) offB[c] = swz_off(wc*64 + 4*frow + c, kq);

  f32x4 acc[4][4] = {};

  auto body = [&](int buf, int s){
    bf16x8 a4[4], b4[4];
    #pragma unroll
    for (int m=0;m<4;m++) a4[m] = *(const bf16x8*)(Lb + 49152 + buf*8192 + offA[m]);
    #pragma unroll
    for (int c=0;c<4;c++) b4[c] = *(const bf16x8*)(Lb + buf*16384 + offB[c]);
    const bool doStage = (s + 2 < NTQ);
    if (doStage){ int nb = buf+2; if (nb>=3) nb-=3; stage(nb, s+2); }
    asm volatile("s_waitcnt lgkmcnt(0)" ::: "memory");
    __builtin_amdgcn_sched_barrier(0);
    __builtin_amdgcn_s_setprio(1);
    #pragma unroll
    for (int m=0;m<4;m++)
      #pragma unroll
      for (int c=0;c<4;c++)
        acc[m][c] = MFMA_(a4[m], b4[c], acc[m][c]);
    __builtin_amdgcn_s_setprio(0);
    __builtin_amdgcn_sched_barrier(0);
    if (s + 1 < NTQ){
      if (doStage) asm volatile("s_waitcnt vmcnt(3)" ::: "memory");
      else         asm volatile("s_waitcnt vmcnt(0)" ::: "memory");
      __builtin_amdgcn_s_barrier();
    }
  };

  stage(0, 0); stage(1, 1);
  asm volatile("s_waitcnt vmcnt(3)" ::: "memory");
  __builtin_amdgcn_s_barrier();

  #pragma unroll
  for (int i = 0; i < 5; i++){
    body(0, i*3);
    body(1, i*3+1);
    body(2, i*3+2);
  }
  body(0, 15);

  const int col4 = wc*64 + 4*frow;
  const int seg = bcol >> 9;
  const int colr = (bcol & 511) + col4;
  if (seg < 2){
    uint8_t* dq = seg==0 ? q8 : k8;
    const float* bp = seg==0 ? bias0 : bias1;
    const float4 bi = *(const float4*)(bp + colr);
    #pragma unroll
    for (int m=0;m<4;m++){
      #pragma unroll
      for (int r=0;r<4;r++){
        const int rr = brow + wr*64 + m*16 + kq*4 + r;
        unsigned int pv = __builtin_amdgcn_cvt_pk_fp8_f32(acc[m][0][r]+bi.x, acc[m][1][r]+bi.y, 0u, false);
        pv = __builtin_amdgcn_cvt_pk_fp8_f32(acc[m][2][r]+bi.z, acc[m][3][r]+bi.w, pv, true);
        *(unsigned int*)&dq[(size_t)rr*NC + colr] = pv;
      }
    }
  } else {
    const float4 bi = *(const float4*)(bias2 + colr);
    const float bvs[4] = {bi.x, bi.y, bi.z, bi.w};
    #pragma unroll
    for (int m=0;m<4;m++){
      const int rr0 = brow + wr*64 + m*16 + kq*4;
      const int b = rr0 >> 12, sq = rr0 & 4095;
      #pragma unroll
      for (int n=0;n<4;n++){
        unsigned int pv = __builtin_amdgcn_cvt_pk_fp8_f32(acc[m][n][0]+bvs[n], acc[m][n][1]+bvs[n], 0u, false);
        pv = __builtin_amdgcn_cvt_pk_fp8_f32(acc[m][n][2]+bvs[n], acc[m][n][3]+bvs[n], pv, true);
        *(unsigned int*)&v8T[((size_t)(b*NC + colr + n) << 12) + sq] = pv;
      }
    }
  }
}

// ====== fp8 8B-granule machinery (qk8 / pv8) ======
__device__ __forceinline__ int rdoff8(int rl, int ks){
  int slot8 = ((rl&1)<<3) | (((((ks>>1) ^ (rl>>1)) & 3))<<1) | (ks&1);
  return ((rl>>1)<<7) + (slot8<<3);
}
__device__ __forceinline__ int cmap64(int p){
  return (p & 192) + (((p & 15) << 2) | ((p >> 4) & 3));
}

// ====== k_qk8 (slim MX): FP8 QK^T via mfma_scale 32x32x64, unit scales ======
// 128x128 tile, 256 thr (4 waves 2x2), per-wave 64x64 = 2x2 32x32 frags.
// BK=64B, ring-3 48KB, (256,3) -> VGPR cap 170 (need ~116; acc 64 + 4xv8i 32),
// 3 blocks/CU. rdoff8 8B-granule swizzle (round-8/11 verified) — 32B MX operand
// assembled from 4 b64 loads at base ^ {0,8,16,24}.
__global__ __launch_bounds__(256, 3) void k_qk8(
    const uint8_t* __restrict__ Q8, const uint8_t* __restrict__ K8,
    uint8_t* __restrict__ P8, float* __restrict__ partsum, float alpha)
{
  __shared__ char LDS[49152];   // 3 bufs x (A 8KB + B 8KB)
  char* Lb = LDS;
  const int t = threadIdx.x;
  const int l = t & 63, w = t >> 6;
  const int wr = w >> 1, wcc = w & 1;
  const int l31 = l & 31, kh = l >> 5;
  // XCD remap: grid (32,32,4) -> nwg=4096
  int f = ((int)blockIdx.z*32 + (int)blockIdx.y)*32 + (int)blockIdx.x;
  f = (f & 7)*512 + (f >> 3);
  const int bx = f & 31; const int t2 = f >> 5;
  const int by = t2 & 31; const int bb = t2 >> 5;
  const int brow = by*128, bcol = bx*128;
  const size_t bOff = (size_t)bb*NSEQ*NC;

  // staging source decode (round-11 machinery; 256 threads cover 2 units each)
  const int Lp = t >> 3, p2 = t & 7;
  const int rlu = 2*Lp + (p2 >> 2);
  const int gru = (p2 & 3) ^ (Lp & 3);
  const uint8_t* Ap0 = Q8 + bOff + (size_t)(brow + rlu)*NC + gru*16;
  const uint8_t* Bp0 = K8 + bOff + (size_t)(bcol + rlu)*NC + gru*16;

  auto stage = [&](int buf, int kt){
    const size_t ko = (size_t)kt*64;
    gll16(Ap0 + ko,                  Lb + buf*16384 + t*16);
    gll16(Ap0 + (size_t)64*NC + ko,  Lb + buf*16384 + 4096 + t*16);
    gll16(Bp0 + ko,                  Lb + buf*16384 + 8192 + t*16);
    gll16(Bp0 + (size_t)64*NC + ko,  Lb + buf*16384 + 12288 + t*16);
  };

  // read base offsets: operand (rl, k-slots kh*4..+3); slots at base^{0,8,16,24}
  const int oA0 = rdoff8(wr*64 +      l31, kh*4);
  const int oA1 = rdoff8(wr*64 + 32 + l31, kh*4);
  const int oB0 = rdoff8(wcc*64 +      l31, kh*4);
  const int oB1 = rdoff8(wcc*64 + 32 + l31, kh*4);

  auto ld32 = [](const char* base, int off)->v8i{
    i64 q0 = *(const i64*)(base + off);
    i64 q1 = *(const i64*)(base + (off^8));
    i64 q2 = *(const i64*)(base + (off^16));
    i64 q3 = *(const i64*)(base + (off^24));
    v8i r;
    r[0]=(int)q0; r[1]=(int)(q0>>32);
    r[2]=(int)q1; r[3]=(int)(q1>>32);
    r[4]=(int)q2; r[5]=(int)(q2>>32);
    r[6]=(int)q3; r[7]=(int)(q3>>32);
    return r;
  };

  f32x16 acc00 = {}, acc01 = {}, acc10 = {}, acc11 = {};

  auto body = [&](int buf, int s){
    const char* Ab = Lb + buf*16384;
    const char* Bb = Lb + buf*16384 + 8192;
    v8i A0 = ld32(Ab, oA0);
    v8i A1 = ld32(Ab, oA1);
    v8i B0 = ld32(Bb, oB0);
    v8i B1 = ld32(Bb, oB1);
    const bool doStage = (s + 2 < 8);
    if (doStage){ int nb = buf+2; if (nb>=3) nb-=3; stage(nb, s+2); }
    asm volatile("s_waitcnt lgkmcnt(0)" ::: "memory");
    __builtin_amdgcn_sched_barrier(0);
    __builtin_amdgcn_s_setprio(1);
    acc00 = MFMAX_(A0, B0, acc00);
    acc01 = MFMAX_(A0, B1, acc01);
    acc10 = MFMAX_(A1, B0, acc10);
    acc11 = MFMAX_(A1, B1, acc11);
    __builtin_amdgcn_s_setprio(0);
    __builtin_amdgcn_sched_barrier(0);
    if (s + 1 < 8){
      if (doStage) asm volatile("s_waitcnt vmcnt(4)" ::: "memory");
      else         asm volatile("s_waitcnt vmcnt(0)" ::: "memory");
      __builtin_amdgcn_s_barrier();
    }
  };

  stage(0, 0); stage(1, 1);
  asm volatile("s_waitcnt vmcnt(4)" ::: "memory");
  __builtin_amdgcn_s_barrier();

  body(0,0); body(1,1); body(2,2); body(0,3);
  body(1,4); body(2,5); body(0,6); body(1,7);

  // epilogue: exp -> fp8 P + f32 row partials.
  // C/D 32x32 layout (m74/m101): col = l&31, row = (reg&3)+8*(reg>>2)+4*(l>>5)
  uint8_t* Pp = P8 + (size_t)bb*NSEQ*NSEQ;
  const int colg = bcol + wcc*64 + l31;
  #pragma unroll
  for (int mi=0; mi<2; mi++){
    const f32x16& ac0 = mi ? acc10 : acc00;
    const f32x16& ac1 = mi ? acc11 : acc01;
    #pragma unroll
    for (int reg=0; reg<16; reg++){
      const int rr = brow + wr*64 + mi*32 + (reg&3) + 8*(reg>>2) + 4*kh;
      float e0 = __expf(alpha*ac0[reg]);
      float e1 = __expf(alpha*ac1[reg]);
      unsigned int c0 = __builtin_amdgcn_cvt_pk_fp8_f32(e0, e0, 0u, false);
      unsigned int c1 = __builtin_amdgcn_cvt_pk_fp8_f32(e1, e1, 0u, false);
      Pp[(size_t)rr*NSEQ + colg]      = (uint8_t)(c0 & 0xFF);
      Pp[(size_t)rr*NSEQ + colg + 32] = (uint8_t)(c1 & 0xFF);
      float rs = e0 + e1;
      rs += __shfl_xor(rs, 1); rs += __shfl_xor(rs, 2);
      rs += __shfl_xor(rs, 4); rs += __shfl_xor(rs, 8);
      rs += __shfl_xor(rs, 16);
      if (l31 == 0)
        partsum[((size_t)bb*NSEQ + rr)*64 + bx*2 + wcc] = rs;
    }
  }
}

// ====== k_pv8: FP8 PV split-K — 128x256, BK=64B, ring-3, 2 blocks/CU ======
__global__ __launch_bounds__(512, 4) void k_pv8(
    const uint8_t* __restrict__ P8, const uint8_t* __restrict__ V8,
    u16* __restrict__ opart)
{
  __shared__ char LDS[73728];
  char* LA = LDS;
  char* LB = LDS + 24576;
  const int t = threadIdx.x;
  const int l = t & 63, w = t >> 6;
  const int wr = w >> 2, wc = w & 3;
  const int frow = l & 15, kq = l >> 4;
  int f = ((int)blockIdx.z*32 + (int)blockIdx.y)*2 + (int)blockIdx.x;
  f = (f & 7)*64 + (f >> 3);
  const int bx = f & 1; const int t2 = f >> 1;
  const int by = t2 & 31; const int bz = t2 >> 5;
  const int bb = bz & 3; const int sp = bz >> 2;
  const int brow = by*128, bcol = bx*256;
  const int kOff = sp*(NSEQ/2);

  const int Lp = t >> 3, p2 = t & 7;
  const int rlu = 2*Lp + (p2 >> 2);
  const int gru = (p2 & 3) ^ (Lp & 3);
  const uint8_t* Ap  = P8 + (size_t)bb*NSEQ*NSEQ + (size_t)(brow + rlu)*NSEQ + kOff + gru*16;
  const uint8_t* Bp0 = V8 + (size_t)bb*NC*NSEQ + (size_t)(bcol + cmap64(rlu))*NSEQ + kOff + gru*16;
  const uint8_t* Bp1 = V8 + (size_t)bb*NC*NSEQ + (size_t)(bcol + cmap64(rlu + 128))*NSEQ + kOff + gru*16;

  auto stage = [&](int buf, int kt){
    const size_t ko = (size_t)kt*64;
    gll16(Ap  + ko, LA + buf*8192 + t*16);
    gll16(Bp0 + ko, LB + buf*16384 + t*16);
    gll16(Bp1 + ko, LB + buf*16384 + 8192 + t*16);
  };

  int offA[4], offB[4];
  #pragma unroll
  for (int m=0;m<4;m++) offA[m] = rdoff8(wr*64 + m*16 + frow, kq);
  #pragma unroll
  for (int n=0;n<4;n++) offB[n] = rdoff8(wc*64 + n*16 + frow, kq);

  f32x4 acc[4][4] = {};

  auto body = [&](int buf, int s){
    i64 a0[4], a1[4], b0[4], b1[4];
    const char* Ab = LA + buf*8192;
    const char* Bb = LB + buf*16384;
    #pragma unroll
    for (int m=0;m<4;m++){ a0[m] = *(const i64*)(Ab + offA[m]); a1[m] = *(const i64*)(Ab + (offA[m]^32)); }
    #pragma unroll
    for (int n=0;n<4;n++){ b0[n] = *(const i64*)(Bb + offB[n]); b1[n] = *(const i64*)(Bb + (offB[n]^32)); }
    const bool doStage = (s + 2 < 32);
    if (doStage){ int nb = buf+2; if (nb>=3) nb-=3; stage(nb, s+2); }
    asm volatile("s_waitcnt lgkmcnt(0)" ::: "memory");
    __builtin_amdgcn_sched_barrier(0);
    __builtin_amdgcn_s_setprio(1);
    #pragma unroll
    for (int m=0;m<4;m++)
      #pragma unroll
      for (int n=0;n<4;n++){
        acc[m][n] = MFMA8_(a0[m], b0[n], acc[m][n]);
        acc[m][n] = MFMA8_(a1[m], b1[n], acc[m][n]);
      }
    __builtin_amdgcn_s_setprio(0);
    __builtin_amdgcn_sched_barrier(0);
    if (s + 1 < 32){
      if (doStage) asm volatile("s_waitcnt vmcnt(3)" ::: "memory");
      else         asm volatile("s_waitcnt vmcnt(0)" ::: "memory");
      __builtin_amdgcn_s_barrier();
    }
  };

  stage(0, 0); stage(1, 1);
  asm volatile("s_waitcnt vmcnt(3)" ::: "memory");
  __builtin_amdgcn_s_barrier();

  #pragma unroll
  for (int i = 0; i < 10; i++){
    body(0, i*3);
    body(1, i*3+1);
    body(2, i*3+2);
  }
  body(0, 30); body(1, 31);

  u16* op = opart + (size_t)sp*NM*NC + (size_t)bb*NSEQ*NC;
  const int col4 = bcol + wc*64 + 4*frow;
  #pragma unroll
  for (int m=0;m<4;m++){
    #pragma unroll
    for (int r=0;r<4;r++){
      const int rr = brow + wr*64 + m*16 + kq*4 + r;
      u32x2 wv;
      wv[0] = pk2(acc[m][0][r], acc[m][1][r]);
      wv[1] = pk2(acc[m][2][r], acc[m][3][r]);
      __builtin_nontemporal_store(wv, (u32x2*)&op[(size_t)rr*NC + col4]);
    }
  }
}

// ====== k_t256o: out-projection — 128x128 tile, 4 waves, BK=32, ring-3, 48KB ======
__global__ __launch_bounds__(256, 3) void k_t256o(
    const u16* __restrict__ A, const u16* __restrict__ B,
    float* __restrict__ out, const float* __restrict__ bias, const float* __restrict__ res)
{
  __shared__ u16 LDS[24576];
  char* Lb = (char*)LDS;
  const int t = threadIdx.x;
  const int l = t & 63, w = t >> 6;
  const int wr = w >> 1, wc = w & 1;
  const int frow = l & 15, kq = l >> 4;
  int f = (int)blockIdx.y*4 + (int)blockIdx.x;
  f = (f & 7)*64 + (f >> 3);
  const int bx = f & 3; const int by = f >> 2;
  const int brow = by*128, bcol = bx*128;

  const int pA = t & 7;
  const int L0 = t >> 3;
  const int rl0 = dec_rl(L0, pA),      kq0 = dec_kq(L0, pA);
  const int rl1 = dec_rl(L0+32, pA),   kq1 = dec_kq(L0+32, pA);
  const u16* Ap0 = A + (size_t)(brow + rl0)*NC + kq0*8;
  const u16* Ap1 = A + (size_t)(brow + rl1)*NC + kq1*8;
  const u16* Bp0 = B + (size_t)(bcol + rl0)*NC + kq0*8;
  const u16* Bp1 = B + (size_t)(bcol + rl1)*NC + kq1*8;

  auto stage = [&](int buf, int kt){
    const size_t ko = (size_t)kt*32;
    gll16(Ap0 + ko, Lb + buf*16384 + t*16);
    gll16(Ap1 + ko, Lb + buf*16384 + 4096 + t*16);
    gll16(Bp0 + ko, Lb + buf*16384 + 8192 + t*16);
    gll16(Bp1 + ko, Lb + buf*16384 + 12288 + t*16);
  };

  int offA[4], offB[4];
  #pragma unroll
  for (int m=0;m<4;m++) offA[m] = swz_off(wr*64 + m*16 + frow, kq);
  #pragma unroll
  for (int c=0;c<4;c++) offB[c] = swz_off(wc*64 + 4*frow + c, kq);

  f32x4 acc[4][4] = {};

  auto body = [&](int buf, int s){
    bf16x8 a4[4], b4[4];
    #pragma unroll
    for (int m=0;m<4;m++) a4[m] = *(const bf16x8*)(Lb + buf*16384 + offA[m]);
    #pragma unroll
    for (int c=0;c<4;c++) b4[c] = *(const bf16x8*)(Lb + buf*16384 + 8192 + offB[c]);
    const bool doStage = (s + 2 < NTQ);
    if (doStage){ int nb = buf+2; if (nb>=3) nb-=3; stage(nb, s+2); }
    asm volatile("s_waitcnt lgkmcnt(0)" ::: "memory");
    __builtin_amdgcn_sched_barrier(0);
    __builtin_amdgcn_s_setprio(1);
    #pragma unroll
    for (int m=0;m<4;m++)
      #pragma unroll
      for (int c=0;c<4;c++)
        acc[m][c] = MFMA_(a4[m], b4[c], acc[m][c]);
    __builtin_amdgcn_s_setprio(0);
    __builtin_amdgcn_sched_barrier(0);
    if (s + 1 < NTQ){
      if (doStage) asm volatile("s_waitcnt vmcnt(4)" ::: "memory");
      else         asm volatile("s_waitcnt vmcnt(0)" ::: "memory");
      __builtin_amdgcn_s_barrier();
    }
  };

  stage(0, 0); stage(1, 1);
  asm volatile("s_waitcnt vmcnt(4)" ::: "memory");
  __builtin_amdgcn_s_barrier();

  #pragma unroll
  for (int i = 0; i < 5; i++){
    body(0, i*3);
    body(1, i*3+1);
    body(2, i*3+2);
  }
  body(0, 15);

  const int c = bcol + wc*64 + 4*frow;
  const float4 bi = *(const float4*)(bias + c);
  #pragma unroll
  for (int m=0;m<4;m++){
    #pragma unroll
    for (int r=0;r<4;r++){
      const int rr = brow + wr*64 + m*16 + kq*4 + r;
      const float4 rv = *(const float4*)(res + (size_t)rr*NC + c);
      float4 ov;
      ov.x = acc[m][0][r] + bi.x + rv.x;
      ov.y = acc[m][1][r] + bi.y + rv.y;
      ov.z = acc[m][2][r] + bi.z + rv.z;
      ov.w = acc[m][3][r] + bi.w + rv.w;
      *(float4*)&out[(size_t)rr*NC + c] = ov;
    }
  }
}

extern "C" void kernel_launch(void* const* d_in, const int* in_sizes, int n_in,
                              void* d_out, int out_size, void* d_ws, size_t ws_size,
                              hipStream_t stream){
  const float* x   = (const float*)d_in[0];
  const float* gsc = (const float*)d_in[1];
  const float* gbi = (const float*)d_in[2];
  const float* wq  = (const float*)d_in[3];
  const float* bq  = (const float*)d_in[4];
  const float* wk  = (const float*)d_in[5];
  const float* bk  = (const float*)d_in[6];
  const float* wv  = (const float*)d_in[7];
  const float* bv  = (const float*)d_in[8];
  const float* wo  = (const float*)d_in[9];
  const float* bo  = (const float*)d_in[10];
  float* out = (float*)d_out;

  char* wsp = (char*)d_ws;
  size_t off = 0;
  auto alloc = [&](size_t bytes)->void*{ void* p = wsp + off; off += (bytes + 255) & ~(size_t)255; return p; };
  float* stats   = (float*)alloc((size_t)NB*NG*2*sizeof(float));
  float* sums    = (float*)alloc((size_t)NM*sizeof(float));
  float* partsum = (float*)alloc((size_t)NM*64*sizeof(float));
  u16* xbf   = (u16*)alloc((size_t)NM*NC*2);   // dead after gn_apply2
  u16* hn    = (u16*)alloc((size_t)NM*NC*2);   // dead after k_qkv
  u16* wqkvT = (u16*)alloc((size_t)3*NC*NC*2);
  u16* woT   = (u16*)alloc((size_t)NC*NC*2);
  uint8_t* q8 = (uint8_t*)alloc((size_t)NM*NC);
  uint8_t* k8 = (uint8_t*)alloc((size_t)NM*NC);
  uint8_t* v8 = (uint8_t*)alloc((size_t)NM*NC);
  u16* o     = (u16*)alloc((size_t)NM*NC*2);
  uint8_t* P8 = (uint8_t*)alloc((size_t)NB*NSEQ*NSEQ);
  u16* opart = xbf;  // PV split-K partials [2][NM][NC] alias xbf+hn (32 MiB, both dead)

  k_zero<<<1,256,0,stream>>>(stats, NB*NG*2);
  k_gn_stats2<<<NB*64,256,0,stream>>>(x, xbf, stats);
  k_gn_apply2<<<4096,256,0,stream>>>(xbf, stats, gsc, gbi, hn);
  k_wtrans4<<<4096,256,0,stream>>>(wq, wk, wv, wo, wqkvT, woT);

  // QKV projection: q,k,v all fp8 out
  k_qkv<<<dim3(6,128,1),512,0,stream>>>(hn, wqkvT, q8, k8, v8, bq, bk, bv);

  const float scale = 0.044194173824159216f;  // 512^-0.5
  // QK^T fp8 via MX-scaled 32x32x64, slim register geometry (256 thr, 3 blocks/CU)
  k_qk8<<<dim3(32,32,NB),256,0,stream>>>(q8, k8, P8, partsum, scale);
  k_sumred<<<NM/4,256,0,stream>>>(partsum, sums);
  // PV fp8 split-K=2 (unchanged)
  k_pv8<<<dim3(2,32,8),512,0,stream>>>(P8, v8, opart);
  k_pvred<<<NM*NC/8/256,256,0,stream>>>(opart, sums, o);
  // output projection + bias + residual
  k_t256o<<<dim3(4,128,1),256,0,stream>>>(o, woT, out, bo, x);
}

// Round 14
// 204.205 us; speedup vs baseline: 2.0807x; 1.5833x over previous
//
#include <hip/hip_runtime.h>
#include <stdint.h>

typedef unsigned short u16;
typedef long i64;
typedef __bf16 bf16x8 __attribute__((ext_vector_type(8)));
typedef float f32x4 __attribute__((ext_vector_type(4)));
typedef uint32_t u32x2 __attribute__((ext_vector_type(2)));
typedef uint32_t u32x4 __attribute__((ext_vector_type(4)));

#define NB 4
#define NC 512
#define NG 32
#define NSEQ 4096
#define NM (NB*NSEQ)

#define MFMA_(a,b,c) __builtin_amdgcn_mfma_f32_16x16x32_bf16(a,b,c,0,0,0)
#define MFMA8_(a,b,c) __builtin_amdgcn_mfma_f32_16x16x32_fp8_fp8(a,b,c,0,0,0)

__device__ __forceinline__ u16 f2bf(float f){
  uint32_t u = __builtin_bit_cast(uint32_t, f);
  u += 0x7FFFu + ((u >> 16) & 1u);
  return (u16)(u >> 16);
}
__device__ __forceinline__ float bfu(uint32_t lo16){
  return __builtin_bit_cast(float, lo16 << 16);
}
__device__ __forceinline__ uint32_t pk2(float a, float b){
  return (uint32_t)f2bf(a) | ((uint32_t)f2bf(b) << 16);
}

__device__ __forceinline__ void gll16(const void* g, void* l){
  __builtin_amdgcn_global_load_lds(
      (const __attribute__((address_space(1))) void*)g,
      (__attribute__((address_space(3))) void*)l, 16, 0, 0);
}

__global__ void k_zero(float* p, int n){
  int i = blockIdx.x*blockDim.x + threadIdx.x;
  if (i < n) p[i] = 0.f;
}

// GN pass 1: row-major read of x, per-group partial sums + bf16 copy of x.
__global__ __launch_bounds__(256) void k_gn_stats2(const float* __restrict__ x,
    u16* __restrict__ xbf, float* __restrict__ stats){
  int blk = blockIdx.x;
  int b = blk >> 6, ch = blk & 63;
  int t = threadIdx.x;
  int colv = t & 127;
  int r0 = ch*64 + (t >> 7);
  const float* xp = x  + (size_t)b*NSEQ*NC + (size_t)r0*NC + colv*4;
  u16* xb       = xbf + (size_t)b*NSEQ*NC + (size_t)r0*NC + colv*4;
  float s1 = 0.f, s2 = 0.f;
  #pragma unroll 4
  for (int i = 0; i < 32; i++){
    float4 v = *(const float4*)(xp + (size_t)i*2*NC);
    s1 += v.x+v.y+v.z+v.w;
    s2 += v.x*v.x+v.y*v.y+v.z*v.z+v.w*v.w;
    ushort4 o; o.x=f2bf(v.x); o.y=f2bf(v.y); o.z=f2bf(v.z); o.w=f2bf(v.w);
    *(ushort4*)(xb + (size_t)i*2*NC) = o;
  }
  s1 += __shfl_xor(s1,1); s2 += __shfl_xor(s2,1);
  s1 += __shfl_xor(s1,2); s2 += __shfl_xor(s2,2);
  __shared__ float ls1[4][16], ls2[4][16];
  int w = t >> 6, l = t & 63;
  if ((l & 3) == 0){ ls1[w][l>>2] = s1; ls2[w][l>>2] = s2; }
  __syncthreads();
  if (t < 32){
    int g = t;
    int wlo = g >> 4;
    float a1 = ls1[wlo][g&15] + ls1[wlo+2][g&15];
    float a2 = ls2[wlo][g&15] + ls2[wlo+2][g&15];
    atomicAdd(&stats[(b*NG+g)*2+0], a1);
    atomicAdd(&stats[(b*NG+g)*2+1], a2);
  }
}

// GN pass 2: read bf16 x-copy, normalize+affine, write hn.
__global__ __launch_bounds__(256) void k_gn_apply2(const u16* __restrict__ xbf,
    const float* __restrict__ stats, const float* __restrict__ gsc,
    const float* __restrict__ gbi, u16* __restrict__ hn){
  const float inv_cnt = 1.f/((float)NSEQ*16.f);
  size_t i = ((size_t)blockIdx.x*256 + threadIdx.x)*8;
  int c = (int)(i & 511);
  int b = (int)(i >> 21);
  int g = c >> 4;
  float s1 = stats[(b*NG+g)*2], s2 = stats[(b*NG+g)*2+1];
  float mean = s1*inv_cnt;
  float rstd = rsqrtf(s2*inv_cnt - mean*mean + 1e-6f);
  u32x4 v = *(const u32x4*)(xbf + i);
  float4 scA = *(const float4*)(gsc + c), scB = *(const float4*)(gsc + c + 4);
  float4 biA = *(const float4*)(gbi + c), biB = *(const float4*)(gbi + c + 4);
  const float sc[8] = {scA.x,scA.y,scA.z,scA.w,scB.x,scB.y,scB.z,scB.w};
  const float bi[8] = {biA.x,biA.y,biA.z,biA.w,biB.x,biB.y,biB.z,biB.w};
  u32x4 o;
  #pragma unroll
  for (int j = 0; j < 4; j++){
    float lo = bfu(v[j] & 0xFFFFu);
    float hi = __builtin_bit_cast(float, v[j] & 0xFFFF0000u);
    o[j] = pk2((lo-mean)*rstd*sc[2*j] + bi[2*j], (hi-mean)*rstd*sc[2*j+1] + bi[2*j+1]);
  }
  *(u32x4*)(hn + i) = o;
}

__global__ __launch_bounds__(256) void k_wtrans4(const float* __restrict__ wq, const float* __restrict__ wk,
    const float* __restrict__ wv, const float* __restrict__ wo,
    u16* __restrict__ wqkvT, u16* __restrict__ woT){
  int j = blockIdx.x*256 + threadIdx.x;
  int wsel = j >> 18, r = j & 262143;
  int n = r >> 9, k = r & 511;
  const float* src = wsel==0?wq : wsel==1?wk : wsel==2?wv : wo;
  u16 v = f2bf(src[k*512 + n]);
  if (wsel < 3) wqkvT[(size_t)wsel*262144 + r] = v;
  else          woT[r] = v;
}

__global__ __launch_bounds__(256) void k_sumred(const float* __restrict__ part, float* __restrict__ sums){
  int row = blockIdx.x*4 + (threadIdx.x >> 6);
  int l = threadIdx.x & 63;
  float s = part[(size_t)row*64 + l];
  #pragma unroll
  for (int o = 32; o; o >>= 1) s += __shfl_xor(s, o);
  if (l == 0) sums[row] = s;
}

__global__ __launch_bounds__(256) void k_pvred(const u16* __restrict__ op, const float* __restrict__ sums,
    u16* __restrict__ o){
  size_t i = ((size_t)blockIdx.x*256 + threadIdx.x)*8;
  int row = (int)(i >> 9);
  float inv = 1.f/sums[row];
  u32x4 a = __builtin_nontemporal_load((const u32x4*)(op + i));
  u32x4 b = __builtin_nontemporal_load((const u32x4*)(op + (size_t)NM*NC + i));
  uint32_t r[4];
  #pragma unroll
  for (int j=0;j<4;j++){
    float lo = (bfu(a[j] & 0xFFFFu) + bfu(b[j] & 0xFFFFu)) * inv;
    float hi = (__builtin_bit_cast(float, a[j] & 0xFFFF0000u) +
                __builtin_bit_cast(float, b[j] & 0xFFFF0000u)) * inv;
    r[j] = (uint32_t)f2bf(lo) | ((uint32_t)f2bf(hi) << 16);
  }
  *(uint4*)(o + i) = make_uint4(r[0], r[1], r[2], r[3]);
}

// ============ bf16 16B-granule swizzle machinery (QKV / out-proj) ============
#define NTQ 16   // K=512 / BK=32 (bf16 kernels)

__device__ __forceinline__ int dec_rl(int L, int p){ return 2*L + ((p>>2) ^ ((L>>1)&1)); }
__device__ __forceinline__ int dec_kq(int L, int p){
  int P01 = ((((L)&1)^((L>>2)&1))<<1) | (((L>>1)&1)^((L>>3)&1));
  return (p&3) ^ P01;
}
__device__ __forceinline__ int swz_off(int rl, int kq){
  int Pq = (((rl&1)^((rl>>2)&1))<<2) | ((((rl>>1)&1)^((rl>>3)&1))<<1) | (((rl>>2)&1)^((rl>>4)&1));
  return ((rl>>1)<<7) + ((Pq ^ kq)<<4);
}

// ====== k_qkv: QKV projection — 128x256 tile, 8 waves, BK=32, ring-3, 2 blocks/CU ======
__global__ __launch_bounds__(512, 4) void k_qkv(
    const u16* __restrict__ A, const u16* __restrict__ B,
    uint8_t* __restrict__ q8, uint8_t* __restrict__ k8, uint8_t* __restrict__ v8T,
    const float* __restrict__ bias0, const float* __restrict__ bias1, const float* __restrict__ bias2)
{
  __shared__ u16 LDS[36864];   // 72 KiB: B 3x16KB @0, A 3x8KB @49152
  char* Lb = (char*)LDS;
  const int t = threadIdx.x;
  const int l = t & 63, w = t >> 6;
  const int wr = w >> 2, wc = w & 3;
  const int frow = l & 15, kq = l >> 4;
  const int nx = gridDim.x, ny = gridDim.y;
  int f = (int)blockIdx.y*nx + (int)blockIdx.x;
  const int nwg = nx*ny;
  f = (f & 7)*(nwg >> 3) + (f >> 3);
  const int bx = f % nx; const int by = f / nx;
  const int brow = by*128, bcol = bx*256;

  const int pA = t & 7;
  const int LA = t >> 3;
  const int LB0 = t >> 3, LB1 = 64 + (t >> 3);
  const int rlA  = dec_rl(LA, pA),  kqA  = dec_kq(LA, pA);
  const int rlB0 = dec_rl(LB0, pA), kqB0 = dec_kq(LB0, pA);
  const int rlB1 = dec_rl(LB1, pA), kqB1 = dec_kq(LB1, pA);
  const u16* Ap  = A + (size_t)(brow + rlA )*NC + kqA*8;
  const u16* Bp0 = B + (size_t)(bcol + rlB0)*NC + kqB0*8;
  const u16* Bp1 = B + (size_t)(bcol + rlB1)*NC + kqB1*8;

  auto stage = [&](int buf, int kt){
    const size_t ko = (size_t)kt*32;
    gll16(Bp0 + ko, Lb + buf*16384 + t*16);
    gll16(Bp1 + ko, Lb + buf*16384 + 8192 + t*16);
    gll16(Ap  + ko, Lb + 49152 + buf*8192 + t*16);
  };

  int offA[4], offB[4];
  #pragma unroll
  for (int m=0;m<4;m++) offA[m] = swz_off(wr*64 + m*16 + frow, kq);
  #pragma unroll
  for (int c=0;c<4;c++) offB[c] = swz_off(wc*64 + 4*frow + c, kq);

  f32x4 acc[4][4] = {};

  auto body = [&](int buf, int s){
    bf16x8 a4[4], b4[4];
    #pragma unroll
    for (int m=0;m<4;m++) a4[m] = *(const bf16x8*)(Lb + 49152 + buf*8192 + offA[m]);
    #pragma unroll
    for (int c=0;c<4;c++) b4[c] = *(const bf16x8*)(Lb + buf*16384 + offB[c]);
    const bool doStage = (s + 2 < NTQ);
    if (doStage){ int nb = buf+2; if (nb>=3) nb-=3; stage(nb, s+2); }
    asm volatile("s_waitcnt lgkmcnt(0)" ::: "memory");
    __builtin_amdgcn_sched_barrier(0);
    __builtin_amdgcn_s_setprio(1);
    #pragma unroll
    for (int m=0;m<4;m++)
      #pragma unroll
      for (int c=0;c<4;c++)
        acc[m][c] = MFMA_(a4[m], b4[c], acc[m][c]);
    __builtin_amdgcn_s_setprio(0);
    __builtin_amdgcn_sched_barrier(0);
    if (s + 1 < NTQ){
      if (doStage) asm volatile("s_waitcnt vmcnt(3)" ::: "memory");
      else         asm volatile("s_waitcnt vmcnt(0)" ::: "memory");
      __builtin_amdgcn_s_barrier();
    }
  };

  stage(0, 0); stage(1, 1);
  asm volatile("s_waitcnt vmcnt(3)" ::: "memory");
  __builtin_amdgcn_s_barrier();

  #pragma unroll
  for (int i = 0; i < 5; i++){
    body(0, i*3);
    body(1, i*3+1);
    body(2, i*3+2);
  }
  body(0, 15);

  const int col4 = wc*64 + 4*frow;
  const int seg = bcol >> 9;
  const int colr = (bcol & 511) + col4;
  if (seg < 2){
    uint8_t* dq = seg==0 ? q8 : k8;
    const float* bp = seg==0 ? bias0 : bias1;
    const float4 bi = *(const float4*)(bp + colr);
    #pragma unroll
    for (int m=0;m<4;m++){
      #pragma unroll
      for (int r=0;r<4;r++){
        const int rr = brow + wr*64 + m*16 + kq*4 + r;
        unsigned int pv = __builtin_amdgcn_cvt_pk_fp8_f32(acc[m][0][r]+bi.x, acc[m][1][r]+bi.y, 0u, false);
        pv = __builtin_amdgcn_cvt_pk_fp8_f32(acc[m][2][r]+bi.z, acc[m][3][r]+bi.w, pv, true);
        *(unsigned int*)&dq[(size_t)rr*NC + colr] = pv;
      }
    }
  } else {
    const float4 bi = *(const float4*)(bias2 + colr);
    const float bvs[4] = {bi.x, bi.y, bi.z, bi.w};
    #pragma unroll
    for (int m=0;m<4;m++){
      const int rr0 = brow + wr*64 + m*16 + kq*4;
      const int b = rr0 >> 12, sq = rr0 & 4095;
      #pragma unroll
      for (int n=0;n<4;n++){
        unsigned int pv = __builtin_amdgcn_cvt_pk_fp8_f32(acc[m][n][0]+bvs[n], acc[m][n][1]+bvs[n], 0u, false);
        pv = __builtin_amdgcn_cvt_pk_fp8_f32(acc[m][n][2]+bvs[n], acc[m][n][3]+bvs[n], pv, true);
        *(unsigned int*)&v8T[((size_t)(b*NC + colr + n) << 12) + sq] = pv;
      }
    }
  }
}

// ====== fp8 8B-granule machinery (qk8 / pv8) ======
__device__ __forceinline__ int rdoff8(int rl, int ks){
  int slot8 = ((rl&1)<<3) | (((((ks>>1) ^ (rl>>1)) & 3))<<1) | (ks&1);
  return ((rl>>1)<<7) + (slot8<<3);
}
__device__ __forceinline__ int cmap64(int p){
  return (p & 192) + (((p & 15) << 2) | ((p >> 4) & 3));
}

// ====== k_qk8: FP8 QK^T — 128x256 tile, BK=64B, ring-3, 2 blocks/CU ======
// Output P in fp8 e4m3, packed u32 stores; f32 row-partials.
__global__ __launch_bounds__(512, 4) void k_qk8(
    const uint8_t* __restrict__ Q8, const uint8_t* __restrict__ K8,
    uint8_t* __restrict__ P8, float* __restrict__ partsum, float alpha)
{
  __shared__ char LDS[73728];
  char* LA = LDS;            // 3 x 8192
  char* LB = LDS + 24576;    // 3 x 16384
  const int t = threadIdx.x;
  const int l = t & 63, w = t >> 6;
  const int wr = w >> 2, wc = w & 3;
  const int frow = l & 15, kq = l >> 4;
  int f = ((int)blockIdx.z*32 + (int)blockIdx.y)*16 + (int)blockIdx.x;
  f = (f & 7)*256 + (f >> 3);
  const int bx = f & 15; const int t2 = f >> 4;
  const int by = t2 & 31; const int bb = t2 >> 5;
  const int brow = by*128, bcol = bx*256;
  const size_t bOff = (size_t)bb*NSEQ*NC;

  const int Lp = t >> 3, p2 = t & 7;
  const int rlu = 2*Lp + (p2 >> 2);
  const int gru = (p2 & 3) ^ (Lp & 3);
  const uint8_t* Ap  = Q8 + bOff + (size_t)(brow + rlu)*NC + gru*16;
  const uint8_t* Bp0 = K8 + bOff + (size_t)(bcol + cmap64(rlu))*NC + gru*16;
  const uint8_t* Bp1 = K8 + bOff + (size_t)(bcol + cmap64(rlu + 128))*NC + gru*16;

  auto stage = [&](int buf, int kt){
    const size_t ko = (size_t)kt*64;
    gll16(Ap  + ko, LA + buf*8192 + t*16);
    gll16(Bp0 + ko, LB + buf*16384 + t*16);
    gll16(Bp1 + ko, LB + buf*16384 + 8192 + t*16);
  };

  int offA[4], offB[4];
  #pragma unroll
  for (int m=0;m<4;m++) offA[m] = rdoff8(wr*64 + m*16 + frow, kq);
  #pragma unroll
  for (int n=0;n<4;n++) offB[n] = rdoff8(wc*64 + n*16 + frow, kq);

  f32x4 acc[4][4] = {};

  auto body = [&](int buf, int s){
    i64 a0[4], a1[4], b0[4], b1[4];
    const char* Ab = LA + buf*8192;
    const char* Bb = LB + buf*16384;
    #pragma unroll
    for (int m=0;m<4;m++){ a0[m] = *(const i64*)(Ab + offA[m]); a1[m] = *(const i64*)(Ab + (offA[m]^32)); }
    #pragma unroll
    for (int n=0;n<4;n++){ b0[n] = *(const i64*)(Bb + offB[n]); b1[n] = *(const i64*)(Bb + (offB[n]^32)); }
    const bool doStage = (s + 2 < 8);
    if (doStage){ int nb = buf+2; if (nb>=3) nb-=3; stage(nb, s+2); }
    asm volatile("s_waitcnt lgkmcnt(0)" ::: "memory");
    __builtin_amdgcn_sched_barrier(0);
    __builtin_amdgcn_s_setprio(1);
    #pragma unroll
    for (int m=0;m<4;m++)
      #pragma unroll
      for (int n=0;n<4;n++){
        acc[m][n] = MFMA8_(a0[m], b0[n], acc[m][n]);
        acc[m][n] = MFMA8_(a1[m], b1[n], acc[m][n]);
      }
    __builtin_amdgcn_s_setprio(0);
    __builtin_amdgcn_sched_barrier(0);
    if (s + 1 < 8){
      if (doStage) asm volatile("s_waitcnt vmcnt(3)" ::: "memory");
      else         asm volatile("s_waitcnt vmcnt(0)" ::: "memory");
      __builtin_amdgcn_s_barrier();
    }
  };

  stage(0, 0); stage(1, 1);
  asm volatile("s_waitcnt vmcnt(3)" ::: "memory");
  __builtin_amdgcn_s_barrier();

  body(0,0); body(1,1); body(2,2); body(0,3);
  body(1,4); body(2,5); body(0,6); body(1,7);

  // epilogue: exp -> fp8 P (packed u32, cols 4*frow..+3) + f32 row partials
  uint8_t* Pp = P8 + (size_t)bb*NSEQ*NSEQ;
  const int colp = bcol + wc*64 + 4*frow;
  #pragma unroll
  for (int m=0;m<4;m++){
    #pragma unroll
    for (int r=0;r<4;r++){
      const int rr = brow + wr*64 + m*16 + kq*4 + r;
      float e0 = __expf(alpha*acc[m][0][r]);
      float e1 = __expf(alpha*acc[m][1][r]);
      float e2 = __expf(alpha*acc[m][2][r]);
      float e3 = __expf(alpha*acc[m][3][r]);
      unsigned int p4 = __builtin_amdgcn_cvt_pk_fp8_f32(e0, e1, 0u, false);
      p4 = __builtin_amdgcn_cvt_pk_fp8_f32(e2, e3, p4, true);
      __builtin_nontemporal_store(p4, (unsigned int*)&Pp[(size_t)rr*NSEQ + colp]);
      float rs = e0 + e1 + e2 + e3;
      rs += __shfl_xor(rs, 1); rs += __shfl_xor(rs, 2);
      rs += __shfl_xor(rs, 4); rs += __shfl_xor(rs, 8);
      if (frow == 0)
        partsum[((size_t)bb*NSEQ + rr)*64 + bx*4 + wc] = rs;
    }
  }
}

// ====== k_pv8: FP8 PV split-K — qk8-clone geometry, NT=32, 2 blocks/CU ======
__global__ __launch_bounds__(512, 4) void k_pv8(
    const uint8_t* __restrict__ P8, const uint8_t* __restrict__ V8,
    u16* __restrict__ opart)
{
  __shared__ char LDS[73728];
  char* LA = LDS;
  char* LB = LDS + 24576;
  const int t = threadIdx.x;
  const int l = t & 63, w = t >> 6;
  const int wr = w >> 2, wc = w & 3;
  const int frow = l & 15, kq = l >> 4;
  int f = ((int)blockIdx.z*32 + (int)blockIdx.y)*2 + (int)blockIdx.x;
  f = (f & 7)*64 + (f >> 3);
  const int bx = f & 1; const int t2 = f >> 1;
  const int by = t2 & 31; const int bz = t2 >> 5;
  const int bb = bz & 3; const int sp = bz >> 2;
  const int brow = by*128, bcol = bx*256;
  const int kOff = sp*(NSEQ/2);

  const int Lp = t >> 3, p2 = t & 7;
  const int rlu = 2*Lp + (p2 >> 2);
  const int gru = (p2 & 3) ^ (Lp & 3);
  const uint8_t* Ap  = P8 + (size_t)bb*NSEQ*NSEQ + (size_t)(brow + rlu)*NSEQ + kOff + gru*16;
  const uint8_t* Bp0 = V8 + (size_t)bb*NC*NSEQ + (size_t)(bcol + cmap64(rlu))*NSEQ + kOff + gru*16;
  const uint8_t* Bp1 = V8 + (size_t)bb*NC*NSEQ + (size_t)(bcol + cmap64(rlu + 128))*NSEQ + kOff + gru*16;

  auto stage = [&](int buf, int kt){
    const size_t ko = (size_t)kt*64;
    gll16(Ap  + ko, LA + buf*8192 + t*16);
    gll16(Bp0 + ko, LB + buf*16384 + t*16);
    gll16(Bp1 + ko, LB + buf*16384 + 8192 + t*16);
  };

  int offA[4], offB[4];
  #pragma unroll
  for (int m=0;m<4;m++) offA[m] = rdoff8(wr*64 + m*16 + frow, kq);
  #pragma unroll
  for (int n=0;n<4;n++) offB[n] = rdoff8(wc*64 + n*16 + frow, kq);

  f32x4 acc[4][4] = {};

  auto body = [&](int buf, int s){
    i64 a0[4], a1[4], b0[4], b1[4];
    const char* Ab = LA + buf*8192;
    const char* Bb = LB + buf*16384;
    #pragma unroll
    for (int m=0;m<4;m++){ a0[m] = *(const i64*)(Ab + offA[m]); a1[m] = *(const i64*)(Ab + (offA[m]^32)); }
    #pragma unroll
    for (int n=0;n<4;n++){ b0[n] = *(const i64*)(Bb + offB[n]); b1[n] = *(const i64*)(Bb + (offB[n]^32)); }
    const bool doStage = (s + 2 < 32);
    if (doStage){ int nb = buf+2; if (nb>=3) nb-=3; stage(nb, s+2); }
    asm volatile("s_waitcnt lgkmcnt(0)" ::: "memory");
    __builtin_amdgcn_sched_barrier(0);
    __builtin_amdgcn_s_setprio(1);
    #pragma unroll
    for (int m=0;m<4;m++)
      #pragma unroll
      for (int n=0;n<4;n++){
        acc[m][n] = MFMA8_(a0[m], b0[n], acc[m][n]);
        acc[m][n] = MFMA8_(a1[m], b1[n], acc[m][n]);
      }
    __builtin_amdgcn_s_setprio(0);
    __builtin_amdgcn_sched_barrier(0);
    if (s + 1 < 32){
      if (doStage) asm volatile("s_waitcnt vmcnt(3)" ::: "memory");
      else         asm volatile("s_waitcnt vmcnt(0)" ::: "memory");
      __builtin_amdgcn_s_barrier();
    }
  };

  stage(0, 0); stage(1, 1);
  asm volatile("s_waitcnt vmcnt(3)" ::: "memory");
  __builtin_amdgcn_s_barrier();

  #pragma unroll
  for (int i = 0; i < 10; i++){
    body(0, i*3);
    body(1, i*3+1);
    body(2, i*3+2);
  }
  body(0, 30); body(1, 31);

  u16* op = opart + (size_t)sp*NM*NC + (size_t)bb*NSEQ*NC;
  const int col4 = bcol + wc*64 + 4*frow;
  #pragma unroll
  for (int m=0;m<4;m++){
    #pragma unroll
    for (int r=0;r<4;r++){
      const int rr = brow + wr*64 + m*16 + kq*4 + r;
      u32x2 wv;
      wv[0] = pk2(acc[m][0][r], acc[m][1][r]);
      wv[1] = pk2(acc[m][2][r], acc[m][3][r]);
      __builtin_nontemporal_store(wv, (u32x2*)&op[(size_t)rr*NC + col4]);
    }
  }
}

// ====== k_t256o: out-projection — 128x128 tile, 4 waves, BK=32, ring-3, 48KB ======
__global__ __launch_bounds__(256, 3) void k_t256o(
    const u16* __restrict__ A, const u16* __restrict__ B,
    float* __restrict__ out, const float* __restrict__ bias, const float* __restrict__ res)
{
  __shared__ u16 LDS[24576];
  char* Lb = (char*)LDS;
  const int t = threadIdx.x;
  const int l = t & 63, w = t >> 6;
  const int wr = w >> 1, wc = w & 1;
  const int frow = l & 15, kq = l >> 4;
  int f = (int)blockIdx.y*4 + (int)blockIdx.x;
  f = (f & 7)*64 + (f >> 3);
  const int bx = f & 3; const int by = f >> 2;
  const int brow = by*128, bcol = bx*128;

  const int pA = t & 7;
  const int L0 = t >> 3;
  const int rl0 = dec_rl(L0, pA),      kq0 = dec_kq(L0, pA);
  const int rl1 = dec_rl(L0+32, pA),   kq1 = dec_kq(L0+32, pA);
  const u16* Ap0 = A + (size_t)(brow + rl0)*NC + kq0*8;
  const u16* Ap1 = A + (size_t)(brow + rl1)*NC + kq1*8;
  const u16* Bp0 = B + (size_t)(bcol + rl0)*NC + kq0*8;
  const u16* Bp1 = B + (size_t)(bcol + rl1)*NC + kq1*8;

  auto stage = [&](int buf, int kt){
    const size_t ko = (size_t)kt*32;
    gll16(Ap0 + ko, Lb + buf*16384 + t*16);
    gll16(Ap1 + ko, Lb + buf*16384 + 4096 + t*16);
    gll16(Bp0 + ko, Lb + buf*16384 + 8192 + t*16);
    gll16(Bp1 + ko, Lb + buf*16384 + 12288 + t*16);
  };

  int offA[4], offB[4];
  #pragma unroll
  for (int m=0;m<4;m++) offA[m] = swz_off(wr*64 + m*16 + frow, kq);
  #pragma unroll
  for (int c=0;c<4;c++) offB[c] = swz_off(wc*64 + 4*frow + c, kq);

  f32x4 acc[4][4] = {};

  auto body = [&](int buf, int s){
    bf16x8 a4[4], b4[4];
    #pragma unroll
    for (int m=0;m<4;m++) a4[m] = *(const bf16x8*)(Lb + buf*16384 + offA[m]);
    #pragma unroll
    for (int c=0;c<4;c++) b4[c] = *(const bf16x8*)(Lb + buf*16384 + 8192 + offB[c]);
    const bool doStage = (s + 2 < NTQ);
    if (doStage){ int nb = buf+2; if (nb>=3) nb-=3; stage(nb, s+2); }
    asm volatile("s_waitcnt lgkmcnt(0)" ::: "memory");
    __builtin_amdgcn_sched_barrier(0);
    __builtin_amdgcn_s_setprio(1);
    #pragma unroll
    for (int m=0;m<4;m++)
      #pragma unroll
      for (int c=0;c<4;c++)
        acc[m][c] = MFMA_(a4[m], b4[c], acc[m][c]);
    __builtin_amdgcn_s_setprio(0);
    __builtin_amdgcn_sched_barrier(0);
    if (s + 1 < NTQ){
      if (doStage) asm volatile("s_waitcnt vmcnt(4)" ::: "memory");
      else         asm volatile("s_waitcnt vmcnt(0)" ::: "memory");
      __builtin_amdgcn_s_barrier();
    }
  };

  stage(0, 0); stage(1, 1);
  asm volatile("s_waitcnt vmcnt(4)" ::: "memory");
  __builtin_amdgcn_s_barrier();

  #pragma unroll
  for (int i = 0; i < 5; i++){
    body(0, i*3);
    body(1, i*3+1);
    body(2, i*3+2);
  }
  body(0, 15);

  const int c = bcol + wc*64 + 4*frow;
  const float4 bi = *(const float4*)(bias + c);
  #pragma unroll
  for (int m=0;m<4;m++){
    #pragma unroll
    for (int r=0;r<4;r++){
      const int rr = brow + wr*64 + m*16 + kq*4 + r;
      const float4 rv = *(const float4*)(res + (size_t)rr*NC + c);
      float4 ov;
      ov.x = acc[m][0][r] + bi.x + rv.x;
      ov.y = acc[m][1][r] + bi.y + rv.y;
      ov.z = acc[m][2][r] + bi.z + rv.z;
      ov.w = acc[m][3][r] + bi.w + rv.w;
      *(float4*)&out[(size_t)rr*NC + c] = ov;
    }
  }
}

extern "C" void kernel_launch(void* const* d_in, const int* in_sizes, int n_in,
                              void* d_out, int out_size, void* d_ws, size_t ws_size,
                              hipStream_t stream){
  const float* x   = (const float*)d_in[0];
  const float* gsc = (const float*)d_in[1];
  const float* gbi = (const float*)d_in[2];
  const float* wq  = (const float*)d_in[3];
  const float* bq  = (const float*)d_in[4];
  const float* wk  = (const float*)d_in[5];
  const float* bk  = (const float*)d_in[6];
  const float* wv  = (const float*)d_in[7];
  const float* bv  = (const float*)d_in[8];
  const float* wo  = (const float*)d_in[9];
  const float* bo  = (const float*)d_in[10];
  float* out = (float*)d_out;

  char* wsp = (char*)d_ws;
  size_t off = 0;
  auto alloc = [&](size_t bytes)->void*{ void* p = wsp + off; off += (bytes + 255) & ~(size_t)255; return p; };
  float* stats   = (float*)alloc((size_t)NB*NG*2*sizeof(float));
  float* sums    = (float*)alloc((size_t)NM*sizeof(float));
  float* partsum = (float*)alloc((size_t)NM*64*sizeof(float));
  u16* xbf   = (u16*)alloc((size_t)NM*NC*2);   // dead after gn_apply2
  u16* hn    = (u16*)alloc((size_t)NM*NC*2);   // dead after k_qkv
  u16* wqkvT = (u16*)alloc((size_t)3*NC*NC*2);
  u16* woT   = (u16*)alloc((size_t)NC*NC*2);
  uint8_t* q8 = (uint8_t*)alloc((size_t)NM*NC);
  uint8_t* k8 = (uint8_t*)alloc((size_t)NM*NC);
  uint8_t* v8 = (uint8_t*)alloc((size_t)NM*NC);
  u16* o     = (u16*)alloc((size_t)NM*NC*2);
  uint8_t* P8 = (uint8_t*)alloc((size_t)NB*NSEQ*NSEQ);
  u16* opart = xbf;  // PV split-K partials [2][NM][NC] alias xbf+hn (32 MiB, both dead)

  k_zero<<<1,256,0,stream>>>(stats, NB*NG*2);
  k_gn_stats2<<<NB*64,256,0,stream>>>(x, xbf, stats);
  k_gn_apply2<<<4096,256,0,stream>>>(xbf, stats, gsc, gbi, hn);
  k_wtrans4<<<4096,256,0,stream>>>(wq, wk, wv, wo, wqkvT, woT);

  // QKV projection: q,k,v all fp8 out
  k_qkv<<<dim3(6,128,1),512,0,stream>>>(hn, wqkvT, q8, k8, v8, bq, bk, bv);

  const float scale = 0.044194173824159216f;  // 512^-0.5
  // QK^T fp8 -> fp8 P + row partials
  k_qk8<<<dim3(16,32,NB),512,0,stream>>>(q8, k8, P8, partsum, scale);
  k_sumred<<<NM/4,256,0,stream>>>(partsum, sums);
  // PV fp8 split-K=2 (qk8-clone structure, 2 blocks/CU)
  k_pv8<<<dim3(2,32,8),512,0,stream>>>(P8, v8, opart);
  k_pvred<<<NM*NC/8/256,256,0,stream>>>(opart, sums, o);
  // output projection + bias + residual
  k_t256o<<<dim3(4,128,1),256,0,stream>>>(o, woT, out, bo, x);
}

// Round 15
// 201.742 us; speedup vs baseline: 2.1061x; 1.0122x over previous
//
#include <hip/hip_runtime.h>
#include <stdint.h>

typedef unsigned short u16;
typedef long i64;
typedef __bf16 bf16x8 __attribute__((ext_vector_type(8)));
typedef float f32x4 __attribute__((ext_vector_type(4)));
typedef uint32_t u32x2 __attribute__((ext_vector_type(2)));
typedef uint32_t u32x4 __attribute__((ext_vector_type(4)));

#define NB 4
#define NC 512
#define NG 32
#define NSEQ 4096
#define NM (NB*NSEQ)

#define MFMA_(a,b,c) __builtin_amdgcn_mfma_f32_16x16x32_bf16(a,b,c,0,0,0)
#define MFMA8_(a,b,c) __builtin_amdgcn_mfma_f32_16x16x32_fp8_fp8(a,b,c,0,0,0)

__device__ __forceinline__ u16 f2bf(float f){
  uint32_t u = __builtin_bit_cast(uint32_t, f);
  u += 0x7FFFu + ((u >> 16) & 1u);
  return (u16)(u >> 16);
}
__device__ __forceinline__ float bfu(uint32_t lo16){
  return __builtin_bit_cast(float, lo16 << 16);
}
__device__ __forceinline__ uint32_t pk2(float a, float b){
  return (uint32_t)f2bf(a) | ((uint32_t)f2bf(b) << 16);
}

__device__ __forceinline__ void gll16(const void* g, void* l){
  __builtin_amdgcn_global_load_lds(
      (const __attribute__((address_space(1))) void*)g,
      (__attribute__((address_space(3))) void*)l, 16, 0, 0);
}

__global__ void k_zero(float* p, int n){
  int i = blockIdx.x*blockDim.x + threadIdx.x;
  if (i < n) p[i] = 0.f;
}

// GN pass 1: row-major read of x, per-group partial sums + bf16 copy of x.
__global__ __launch_bounds__(256) void k_gn_stats2(const float* __restrict__ x,
    u16* __restrict__ xbf, float* __restrict__ stats){
  int blk = blockIdx.x;
  int b = blk >> 6, ch = blk & 63;
  int t = threadIdx.x;
  int colv = t & 127;
  int r0 = ch*64 + (t >> 7);
  const float* xp = x  + (size_t)b*NSEQ*NC + (size_t)r0*NC + colv*4;
  u16* xb       = xbf + (size_t)b*NSEQ*NC + (size_t)r0*NC + colv*4;
  float s1 = 0.f, s2 = 0.f;
  #pragma unroll 4
  for (int i = 0; i < 32; i++){
    float4 v = *(const float4*)(xp + (size_t)i*2*NC);
    s1 += v.x+v.y+v.z+v.w;
    s2 += v.x*v.x+v.y*v.y+v.z*v.z+v.w*v.w;
    ushort4 o; o.x=f2bf(v.x); o.y=f2bf(v.y); o.z=f2bf(v.z); o.w=f2bf(v.w);
    *(ushort4*)(xb + (size_t)i*2*NC) = o;
  }
  s1 += __shfl_xor(s1,1); s2 += __shfl_xor(s2,1);
  s1 += __shfl_xor(s1,2); s2 += __shfl_xor(s2,2);
  __shared__ float ls1[4][16], ls2[4][16];
  int w = t >> 6, l = t & 63;
  if ((l & 3) == 0){ ls1[w][l>>2] = s1; ls2[w][l>>2] = s2; }
  __syncthreads();
  if (t < 32){
    int g = t;
    int wlo = g >> 4;
    float a1 = ls1[wlo][g&15] + ls1[wlo+2][g&15];
    float a2 = ls2[wlo][g&15] + ls2[wlo+2][g&15];
    atomicAdd(&stats[(b*NG+g)*2+0], a1);
    atomicAdd(&stats[(b*NG+g)*2+1], a2);
  }
}

// GN pass 2: read bf16 x-copy, normalize+affine, write hn.
__global__ __launch_bounds__(256) void k_gn_apply2(const u16* __restrict__ xbf,
    const float* __restrict__ stats, const float* __restrict__ gsc,
    const float* __restrict__ gbi, u16* __restrict__ hn){
  const float inv_cnt = 1.f/((float)NSEQ*16.f);
  size_t i = ((size_t)blockIdx.x*256 + threadIdx.x)*8;
  int c = (int)(i & 511);
  int b = (int)(i >> 21);
  int g = c >> 4;
  float s1 = stats[(b*NG+g)*2], s2 = stats[(b*NG+g)*2+1];
  float mean = s1*inv_cnt;
  float rstd = rsqrtf(s2*inv_cnt - mean*mean + 1e-6f);
  u32x4 v = *(const u32x4*)(xbf + i);
  float4 scA = *(const float4*)(gsc + c), scB = *(const float4*)(gsc + c + 4);
  float4 biA = *(const float4*)(gbi + c), biB = *(const float4*)(gbi + c + 4);
  const float sc[8] = {scA.x,scA.y,scA.z,scA.w,scB.x,scB.y,scB.z,scB.w};
  const float bi[8] = {biA.x,biA.y,biA.z,biA.w,biB.x,biB.y,biB.z,biB.w};
  u32x4 o;
  #pragma unroll
  for (int j = 0; j < 4; j++){
    float lo = bfu(v[j] & 0xFFFFu);
    float hi = __builtin_bit_cast(float, v[j] & 0xFFFF0000u);
    o[j] = pk2((lo-mean)*rstd*sc[2*j] + bi[2*j], (hi-mean)*rstd*sc[2*j+1] + bi[2*j+1]);
  }
  *(u32x4*)(hn + i) = o;
}

__global__ __launch_bounds__(256) void k_wtrans4(const float* __restrict__ wq, const float* __restrict__ wk,
    const float* __restrict__ wv, const float* __restrict__ wo,
    u16* __restrict__ wqkvT, u16* __restrict__ woT){
  int j = blockIdx.x*256 + threadIdx.x;
  int wsel = j >> 18, r = j & 262143;
  int n = r >> 9, k = r & 511;
  const float* src = wsel==0?wq : wsel==1?wk : wsel==2?wv : wo;
  u16 v = f2bf(src[k*512 + n]);
  if (wsel < 3) wqkvT[(size_t)wsel*262144 + r] = v;
  else          woT[r] = v;
}

__global__ __launch_bounds__(256) void k_sumred(const float* __restrict__ part, float* __restrict__ sums){
  int row = blockIdx.x*4 + (threadIdx.x >> 6);
  int l = threadIdx.x & 63;
  float s = part[(size_t)row*64 + l];
  #pragma unroll
  for (int o = 32; o; o >>= 1) s += __shfl_xor(s, o);
  if (l == 0) sums[row] = s;
}

// ============ bf16 16B-granule swizzle machinery (QKV / out-proj) ============
#define NTQ 16   // K=512 / BK=32 (bf16 kernels)

__device__ __forceinline__ int dec_rl(int L, int p){ return 2*L + ((p>>2) ^ ((L>>1)&1)); }
__device__ __forceinline__ int dec_kq(int L, int p){
  int P01 = ((((L)&1)^((L>>2)&1))<<1) | (((L>>1)&1)^((L>>3)&1));
  return (p&3) ^ P01;
}
__device__ __forceinline__ int swz_off(int rl, int kq){
  int Pq = (((rl&1)^((rl>>2)&1))<<2) | ((((rl>>1)&1)^((rl>>3)&1))<<1) | (((rl>>2)&1)^((rl>>4)&1));
  return ((rl>>1)<<7) + ((Pq ^ kq)<<4);
}

// ====== k_qkv: QKV projection — 128x256 tile, 8 waves, BK=32, ring-3, 2 blocks/CU ======
__global__ __launch_bounds__(512, 4) void k_qkv(
    const u16* __restrict__ A, const u16* __restrict__ B,
    uint8_t* __restrict__ q8, uint8_t* __restrict__ k8, uint8_t* __restrict__ v8T,
    const float* __restrict__ bias0, const float* __restrict__ bias1, const float* __restrict__ bias2)
{
  __shared__ u16 LDS[36864];   // 72 KiB: B 3x16KB @0, A 3x8KB @49152
  char* Lb = (char*)LDS;
  const int t = threadIdx.x;
  const int l = t & 63, w = t >> 6;
  const int wr = w >> 2, wc = w & 3;
  const int frow = l & 15, kq = l >> 4;
  const int nx = gridDim.x, ny = gridDim.y;
  int f = (int)blockIdx.y*nx + (int)blockIdx.x;
  const int nwg = nx*ny;
  f = (f & 7)*(nwg >> 3) + (f >> 3);
  const int bx = f % nx; const int by = f / nx;
  const int brow = by*128, bcol = bx*256;

  const int pA = t & 7;
  const int LA = t >> 3;
  const int LB0 = t >> 3, LB1 = 64 + (t >> 3);
  const int rlA  = dec_rl(LA, pA),  kqA  = dec_kq(LA, pA);
  const int rlB0 = dec_rl(LB0, pA), kqB0 = dec_kq(LB0, pA);
  const int rlB1 = dec_rl(LB1, pA), kqB1 = dec_kq(LB1, pA);
  const u16* Ap  = A + (size_t)(brow + rlA )*NC + kqA*8;
  const u16* Bp0 = B + (size_t)(bcol + rlB0)*NC + kqB0*8;
  const u16* Bp1 = B + (size_t)(bcol + rlB1)*NC + kqB1*8;

  auto stage = [&](int buf, int kt){
    const size_t ko = (size_t)kt*32;
    gll16(Bp0 + ko, Lb + buf*16384 + t*16);
    gll16(Bp1 + ko, Lb + buf*16384 + 8192 + t*16);
    gll16(Ap  + ko, Lb + 49152 + buf*8192 + t*16);
  };

  int offA[4], offB[4];
  #pragma unroll
  for (int m=0;m<4;m++) offA[m] = swz_off(wr*64 + m*16 + frow, kq);
  #pragma unroll
  for (int c=0;c<4;c++) offB[c] = swz_off(wc*64 + 4*frow + c, kq);

  f32x4 acc[4][4] = {};

  auto body = [&](int buf, int s){
    bf16x8 a4[4], b4[4];
    #pragma unroll
    for (int m=0;m<4;m++) a4[m] = *(const bf16x8*)(Lb + 49152 + buf*8192 + offA[m]);
    #pragma unroll
    for (int c=0;c<4;c++) b4[c] = *(const bf16x8*)(Lb + buf*16384 + offB[c]);
    const bool doStage = (s + 2 < NTQ);
    if (doStage){ int nb = buf+2; if (nb>=3) nb-=3; stage(nb, s+2); }
    asm volatile("s_waitcnt lgkmcnt(0)" ::: "memory");
    __builtin_amdgcn_sched_barrier(0);
    __builtin_amdgcn_s_setprio(1);
    #pragma unroll
    for (int m=0;m<4;m++)
      #pragma unroll
      for (int c=0;c<4;c++)
        acc[m][c] = MFMA_(a4[m], b4[c], acc[m][c]);
    __builtin_amdgcn_s_setprio(0);
    __builtin_amdgcn_sched_barrier(0);
    if (s + 1 < NTQ){
      if (doStage) asm volatile("s_waitcnt vmcnt(3)" ::: "memory");
      else         asm volatile("s_waitcnt vmcnt(0)" ::: "memory");
      __builtin_amdgcn_s_barrier();
    }
  };

  stage(0, 0); stage(1, 1);
  asm volatile("s_waitcnt vmcnt(3)" ::: "memory");
  __builtin_amdgcn_s_barrier();

  #pragma unroll
  for (int i = 0; i < 5; i++){
    body(0, i*3);
    body(1, i*3+1);
    body(2, i*3+2);
  }
  body(0, 15);

  const int col4 = wc*64 + 4*frow;
  const int seg = bcol >> 9;
  const int colr = (bcol & 511) + col4;
  if (seg < 2){
    uint8_t* dq = seg==0 ? q8 : k8;
    const float* bp = seg==0 ? bias0 : bias1;
    const float4 bi = *(const float4*)(bp + colr);
    #pragma unroll
    for (int m=0;m<4;m++){
      #pragma unroll
      for (int r=0;r<4;r++){
        const int rr = brow + wr*64 + m*16 + kq*4 + r;
        unsigned int pv = __builtin_amdgcn_cvt_pk_fp8_f32(acc[m][0][r]+bi.x, acc[m][1][r]+bi.y, 0u, false);
        pv = __builtin_amdgcn_cvt_pk_fp8_f32(acc[m][2][r]+bi.z, acc[m][3][r]+bi.w, pv, true);
        *(unsigned int*)&dq[(size_t)rr*NC + colr] = pv;
      }
    }
  } else {
    const float4 bi = *(const float4*)(bias2 + colr);
    const float bvs[4] = {bi.x, bi.y, bi.z, bi.w};
    #pragma unroll
    for (int m=0;m<4;m++){
      const int rr0 = brow + wr*64 + m*16 + kq*4;
      const int b = rr0 >> 12, sq = rr0 & 4095;
      #pragma unroll
      for (int n=0;n<4;n++){
        unsigned int pv = __builtin_amdgcn_cvt_pk_fp8_f32(acc[m][n][0]+bvs[n], acc[m][n][1]+bvs[n], 0u, false);
        pv = __builtin_amdgcn_cvt_pk_fp8_f32(acc[m][n][2]+bvs[n], acc[m][n][3]+bvs[n], pv, true);
        *(unsigned int*)&v8T[((size_t)(b*NC + colr + n) << 12) + sq] = pv;
      }
    }
  }
}

// ====== fp8 8B-granule machinery (qk8 / pv8f) ======
__device__ __forceinline__ int rdoff8(int rl, int ks){
  int slot8 = ((rl&1)<<3) | (((((ks>>1) ^ (rl>>1)) & 3))<<1) | (ks&1);
  return ((rl>>1)<<7) + (slot8<<3);
}
__device__ __forceinline__ int cmap64(int p){
  return (p & 192) + (((p & 15) << 2) | ((p >> 4) & 3));
}

// ====== k_qk8: FP8 QK^T — 128x256 tile, BK=64B, ring-3, 2 blocks/CU (round-11) ======
__global__ __launch_bounds__(512, 4) void k_qk8(
    const uint8_t* __restrict__ Q8, const uint8_t* __restrict__ K8,
    uint8_t* __restrict__ P8, float* __restrict__ partsum, float alpha)
{
  __shared__ char LDS[73728];
  char* LA = LDS;            // 3 x 8192
  char* LB = LDS + 24576;    // 3 x 16384
  const int t = threadIdx.x;
  const int l = t & 63, w = t >> 6;
  const int wr = w >> 2, wc = w & 3;
  const int frow = l & 15, kq = l >> 4;
  int f = ((int)blockIdx.z*32 + (int)blockIdx.y)*16 + (int)blockIdx.x;
  f = (f & 7)*256 + (f >> 3);
  const int bx = f & 15; const int t2 = f >> 4;
  const int by = t2 & 31; const int bb = t2 >> 5;
  const int brow = by*128, bcol = bx*256;
  const size_t bOff = (size_t)bb*NSEQ*NC;

  const int Lp = t >> 3, p2 = t & 7;
  const int rlu = 2*Lp + (p2 >> 2);
  const int gru = (p2 & 3) ^ (Lp & 3);
  const uint8_t* Ap  = Q8 + bOff + (size_t)(brow + rlu)*NC + gru*16;
  const uint8_t* Bp0 = K8 + bOff + (size_t)(bcol + cmap64(rlu))*NC + gru*16;
  const uint8_t* Bp1 = K8 + bOff + (size_t)(bcol + cmap64(rlu + 128))*NC + gru*16;

  auto stage = [&](int buf, int kt){
    const size_t ko = (size_t)kt*64;
    gll16(Ap  + ko, LA + buf*8192 + t*16);
    gll16(Bp0 + ko, LB + buf*16384 + t*16);
    gll16(Bp1 + ko, LB + buf*16384 + 8192 + t*16);
  };

  int offA[4], offB[4];
  #pragma unroll
  for (int m=0;m<4;m++) offA[m] = rdoff8(wr*64 + m*16 + frow, kq);
  #pragma unroll
  for (int n=0;n<4;n++) offB[n] = rdoff8(wc*64 + n*16 + frow, kq);

  f32x4 acc[4][4] = {};

  auto body = [&](int buf, int s){
    i64 a0[4], a1[4], b0[4], b1[4];
    const char* Ab = LA + buf*8192;
    const char* Bb = LB + buf*16384;
    #pragma unroll
    for (int m=0;m<4;m++){ a0[m] = *(const i64*)(Ab + offA[m]); a1[m] = *(const i64*)(Ab + (offA[m]^32)); }
    #pragma unroll
    for (int n=0;n<4;n++){ b0[n] = *(const i64*)(Bb + offB[n]); b1[n] = *(const i64*)(Bb + (offB[n]^32)); }
    const bool doStage = (s + 2 < 8);
    if (doStage){ int nb = buf+2; if (nb>=3) nb-=3; stage(nb, s+2); }
    asm volatile("s_waitcnt lgkmcnt(0)" ::: "memory");
    __builtin_amdgcn_sched_barrier(0);
    __builtin_amdgcn_s_setprio(1);
    #pragma unroll
    for (int m=0;m<4;m++)
      #pragma unroll
      for (int n=0;n<4;n++){
        acc[m][n] = MFMA8_(a0[m], b0[n], acc[m][n]);
        acc[m][n] = MFMA8_(a1[m], b1[n], acc[m][n]);
      }
    __builtin_amdgcn_s_setprio(0);
    __builtin_amdgcn_sched_barrier(0);
    if (s + 1 < 8){
      if (doStage) asm volatile("s_waitcnt vmcnt(3)" ::: "memory");
      else         asm volatile("s_waitcnt vmcnt(0)" ::: "memory");
      __builtin_amdgcn_s_barrier();
    }
  };

  stage(0, 0); stage(1, 1);
  asm volatile("s_waitcnt vmcnt(3)" ::: "memory");
  __builtin_amdgcn_s_barrier();

  body(0,0); body(1,1); body(2,2); body(0,3);
  body(1,4); body(2,5); body(0,6); body(1,7);

  uint8_t* Pp = P8 + (size_t)bb*NSEQ*NSEQ;
  const int colp = bcol + wc*64 + 4*frow;
  #pragma unroll
  for (int m=0;m<4;m++){
    #pragma unroll
    for (int r=0;r<4;r++){
      const int rr = brow + wr*64 + m*16 + kq*4 + r;
      float e0 = __expf(alpha*acc[m][0][r]);
      float e1 = __expf(alpha*acc[m][1][r]);
      float e2 = __expf(alpha*acc[m][2][r]);
      float e3 = __expf(alpha*acc[m][3][r]);
      unsigned int p4 = __builtin_amdgcn_cvt_pk_fp8_f32(e0, e1, 0u, false);
      p4 = __builtin_amdgcn_cvt_pk_fp8_f32(e2, e3, p4, true);
      __builtin_nontemporal_store(p4, (unsigned int*)&Pp[(size_t)rr*NSEQ + colp]);
      float rs = e0 + e1 + e2 + e3;
      rs += __shfl_xor(rs, 1); rs += __shfl_xor(rs, 2);
      rs += __shfl_xor(rs, 4); rs += __shfl_xor(rs, 8);
      if (frow == 0)
        partsum[((size_t)bb*NSEQ + rr)*64 + bx*4 + wc] = rs;
    }
  }
}

// ====== k_pv8f: FP8 PV full-K — 128x128 tile, 256 thr, ring-3 48KB, 3 blocks/CU ======
// No split-K: NT=64, epilogue applies 1/rowsum and writes final o (bf16 packed).
// Eliminates opart round-trip + k_pvred. cmap64 source-permute on V channels
// gives lane frow's 4 n-values = 4 consecutive channels (round-11 mechanism).
__global__ __launch_bounds__(256, 3) void k_pv8f(
    const uint8_t* __restrict__ P8, const uint8_t* __restrict__ V8,
    const float* __restrict__ sums, u16* __restrict__ o)
{
  __shared__ char LDS[49152];   // 3 bufs x (A 8KB + B 8KB)
  char* Lb = LDS;
  const int t = threadIdx.x;
  const int l = t & 63, w = t >> 6;
  const int wr = w >> 1, wc = w & 1;
  const int frow = l & 15, kq = l >> 4;
  // XCD remap: grid (4,32,4) -> nwg=512
  int f = ((int)blockIdx.z*32 + (int)blockIdx.y)*4 + (int)blockIdx.x;
  f = (f & 7)*64 + (f >> 3);
  const int bx = f & 3; const int t2 = f >> 2;
  const int by = t2 & 31; const int bb = t2 >> 5;
  const int brow = by*128, bcol = bx*128;

  // staging decode: thread t covers A rows rlu, rlu+64 and V chans cmap64(rlu), cmap64(rlu+64)
  const int Lp = t >> 3, p2 = t & 7;
  const int rlu = 2*Lp + (p2 >> 2);
  const int gru = (p2 & 3) ^ (Lp & 3);
  const uint8_t* Ap0 = P8 + (size_t)bb*NSEQ*NSEQ + (size_t)(brow + rlu)*NSEQ + gru*16;
  const uint8_t* Ap1 = P8 + (size_t)bb*NSEQ*NSEQ + (size_t)(brow + rlu + 64)*NSEQ + gru*16;
  const uint8_t* Bp0 = V8 + (size_t)bb*NC*NSEQ + (size_t)(bcol + cmap64(rlu))*NSEQ + gru*16;
  const uint8_t* Bp1 = V8 + (size_t)bb*NC*NSEQ + (size_t)(bcol + cmap64(rlu + 64))*NSEQ + gru*16;

  auto stage = [&](int buf, int kt){
    const size_t ko = (size_t)kt*64;
    gll16(Ap0 + ko, Lb + buf*16384 + t*16);
    gll16(Ap1 + ko, Lb + buf*16384 + 4096 + t*16);
    gll16(Bp0 + ko, Lb + buf*16384 + 8192 + t*16);
    gll16(Bp1 + ko, Lb + buf*16384 + 12288 + t*16);
  };

  int offA[4], offB[4];
  #pragma unroll
  for (int m=0;m<4;m++) offA[m] = rdoff8(wr*64 + m*16 + frow, kq);
  #pragma unroll
  for (int n=0;n<4;n++) offB[n] = rdoff8(wc*64 + n*16 + frow, kq);

  f32x4 acc[4][4] = {};

  auto body = [&](int buf, int s){
    i64 a0[4], a1[4], b0[4], b1[4];
    const char* Ab = Lb + buf*16384;
    const char* Bb = Lb + buf*16384 + 8192;
    #pragma unroll
    for (int m=0;m<4;m++){ a0[m] = *(const i64*)(Ab + offA[m]); a1[m] = *(const i64*)(Ab + (offA[m]^32)); }
    #pragma unroll
    for (int n=0;n<4;n++){ b0[n] = *(const i64*)(Bb + offB[n]); b1[n] = *(const i64*)(Bb + (offB[n]^32)); }
    const bool doStage = (s + 2 < 64);
    if (doStage){ int nb = buf+2; if (nb>=3) nb-=3; stage(nb, s+2); }
    asm volatile("s_waitcnt lgkmcnt(0)" ::: "memory");
    __builtin_amdgcn_sched_barrier(0);
    __builtin_amdgcn_s_setprio(1);
    #pragma unroll
    for (int m=0;m<4;m++)
      #pragma unroll
      for (int n=0;n<4;n++){
        acc[m][n] = MFMA8_(a0[m], b0[n], acc[m][n]);
        acc[m][n] = MFMA8_(a1[m], b1[n], acc[m][n]);
      }
    __builtin_amdgcn_s_setprio(0);
    __builtin_amdgcn_sched_barrier(0);
    if (s + 1 < 64){
      if (doStage) asm volatile("s_waitcnt vmcnt(4)" ::: "memory");
      else         asm volatile("s_waitcnt vmcnt(0)" ::: "memory");
      __builtin_amdgcn_s_barrier();
    }
  };

  stage(0, 0); stage(1, 1);
  asm volatile("s_waitcnt vmcnt(4)" ::: "memory");
  __builtin_amdgcn_s_barrier();

  #pragma unroll 1
  for (int i = 0; i < 21; i++){
    body(0, i*3);
    body(1, i*3+1);
    body(2, i*3+2);
  }
  body(0, 63);

  // epilogue: scale by 1/rowsum, packed bf16 stores (4 consecutive channels)
  u16* op = o + (size_t)bb*NSEQ*NC;
  const int col4 = bcol + wc*64 + 4*frow;
  #pragma unroll
  for (int m=0;m<4;m++){
    #pragma unroll
    for (int r=0;r<4;r++){
      const int rr = brow + wr*64 + m*16 + kq*4 + r;
      const float inv = 1.f/sums[(size_t)bb*NSEQ + rr];
      u32x2 wv;
      wv[0] = pk2(acc[m][0][r]*inv, acc[m][1][r]*inv);
      wv[1] = pk2(acc[m][2][r]*inv, acc[m][3][r]*inv);
      __builtin_nontemporal_store(wv, (u32x2*)&op[(size_t)rr*NC + col4]);
    }
  }
}

// ====== k_t256o: out-projection — 128x128 tile, 4 waves, BK=32, ring-3, 48KB ======
__global__ __launch_bounds__(256, 3) void k_t256o(
    const u16* __restrict__ A, const u16* __restrict__ B,
    float* __restrict__ out, const float* __restrict__ bias, const float* __restrict__ res)
{
  __shared__ u16 LDS[24576];
  char* Lb = (char*)LDS;
  const int t = threadIdx.x;
  const int l = t & 63, w = t >> 6;
  const int wr = w >> 1, wc = w & 1;
  const int frow = l & 15, kq = l >> 4;
  int f = (int)blockIdx.y*4 + (int)blockIdx.x;
  f = (f & 7)*64 + (f >> 3);
  const int bx = f & 3; const int by = f >> 2;
  const int brow = by*128, bcol = bx*128;

  const int pA = t & 7;
  const int L0 = t >> 3;
  const int rl0 = dec_rl(L0, pA),      kq0 = dec_kq(L0, pA);
  const int rl1 = dec_rl(L0+32, pA),   kq1 = dec_kq(L0+32, pA);
  const u16* Ap0 = A + (size_t)(brow + rl0)*NC + kq0*8;
  const u16* Ap1 = A + (size_t)(brow + rl1)*NC + kq1*8;
  const u16* Bp0 = B + (size_t)(bcol + rl0)*NC + kq0*8;
  const u16* Bp1 = B + (size_t)(bcol + rl1)*NC + kq1*8;

  auto stage = [&](int buf, int kt){
    const size_t ko = (size_t)kt*32;
    gll16(Ap0 + ko, Lb + buf*16384 + t*16);
    gll16(Ap1 + ko, Lb + buf*16384 + 4096 + t*16);
    gll16(Bp0 + ko, Lb + buf*16384 + 8192 + t*16);
    gll16(Bp1 + ko, Lb + buf*16384 + 12288 + t*16);
  };

  int offA[4], offB[4];
  #pragma unroll
  for (int m=0;m<4;m++) offA[m] = swz_off(wr*64 + m*16 + frow, kq);
  #pragma unroll
  for (int c=0;c<4;c++) offB[c] = swz_off(wc*64 + 4*frow + c, kq);

  f32x4 acc[4][4] = {};

  auto body = [&](int buf, int s){
    bf16x8 a4[4], b4[4];
    #pragma unroll
    for (int m=0;m<4;m++) a4[m] = *(const bf16x8*)(Lb + buf*16384 + offA[m]);
    #pragma unroll
    for (int c=0;c<4;c++) b4[c] = *(const bf16x8*)(Lb + buf*16384 + 8192 + offB[c]);
    const bool doStage = (s + 2 < NTQ);
    if (doStage){ int nb = buf+2; if (nb>=3) nb-=3; stage(nb, s+2); }
    asm volatile("s_waitcnt lgkmcnt(0)" ::: "memory");
    __builtin_amdgcn_sched_barrier(0);
    __builtin_amdgcn_s_setprio(1);
    #pragma unroll
    for (int m=0;m<4;m++)
      #pragma unroll
      for (int c=0;c<4;c++)
        acc[m][c] = MFMA_(a4[m], b4[c], acc[m][c]);
    __builtin_amdgcn_s_setprio(0);
    __builtin_amdgcn_sched_barrier(0);
    if (s + 1 < NTQ){
      if (doStage) asm volatile("s_waitcnt vmcnt(4)" ::: "memory");
      else         asm volatile("s_waitcnt vmcnt(0)" ::: "memory");
      __builtin_amdgcn_s_barrier();
    }
  };

  stage(0, 0); stage(1, 1);
  asm volatile("s_waitcnt vmcnt(4)" ::: "memory");
  __builtin_amdgcn_s_barrier();

  #pragma unroll
  for (int i = 0; i < 5; i++){
    body(0, i*3);
    body(1, i*3+1);
    body(2, i*3+2);
  }
  body(0, 15);

  const int c = bcol + wc*64 + 4*frow;
  const float4 bi = *(const float4*)(bias + c);
  #pragma unroll
  for (int m=0;m<4;m++){
    #pragma unroll
    for (int r=0;r<4;r++){
      const int rr = brow + wr*64 + m*16 + kq*4 + r;
      const float4 rv = *(const float4*)(res + (size_t)rr*NC + c);
      float4 ov;
      ov.x = acc[m][0][r] + bi.x + rv.x;
      ov.y = acc[m][1][r] + bi.y + rv.y;
      ov.z = acc[m][2][r] + bi.z + rv.z;
      ov.w = acc[m][3][r] + bi.w + rv.w;
      *(float4*)&out[(size_t)rr*NC + c] = ov;
    }
  }
}

extern "C" void kernel_launch(void* const* d_in, const int* in_sizes, int n_in,
                              void* d_out, int out_size, void* d_ws, size_t ws_size,
                              hipStream_t stream){
  const float* x   = (const float*)d_in[0];
  const float* gsc = (const float*)d_in[1];
  const float* gbi = (const float*)d_in[2];
  const float* wq  = (const float*)d_in[3];
  const float* bq  = (const float*)d_in[4];
  const float* wk  = (const float*)d_in[5];
  const float* bk  = (const float*)d_in[6];
  const float* wv  = (const float*)d_in[7];
  const float* bv  = (const float*)d_in[8];
  const float* wo  = (const float*)d_in[9];
  const float* bo  = (const float*)d_in[10];
  float* out = (float*)d_out;

  char* wsp = (char*)d_ws;
  size_t off = 0;
  auto alloc = [&](size_t bytes)->void*{ void* p = wsp + off; off += (bytes + 255) & ~(size_t)255; return p; };
  float* stats   = (float*)alloc((size_t)NB*NG*2*sizeof(float));
  float* sums    = (float*)alloc((size_t)NM*sizeof(float));
  float* partsum = (float*)alloc((size_t)NM*64*sizeof(float));
  u16* xbf   = (u16*)alloc((size_t)NM*NC*2);   // dead after gn_apply2
  u16* hn    = (u16*)alloc((size_t)NM*NC*2);   // dead after k_qkv
  u16* wqkvT = (u16*)alloc((size_t)3*NC*NC*2);
  u16* woT   = (u16*)alloc((size_t)NC*NC*2);
  uint8_t* q8 = (uint8_t*)alloc((size_t)NM*NC);
  uint8_t* k8 = (uint8_t*)alloc((size_t)NM*NC);
  uint8_t* v8 = (uint8_t*)alloc((size_t)NM*NC);
  u16* o     = (u16*)alloc((size_t)NM*NC*2);
  uint8_t* P8 = (uint8_t*)alloc((size_t)NB*NSEQ*NSEQ);

  k_zero<<<1,256,0,stream>>>(stats, NB*NG*2);
  k_gn_stats2<<<NB*64,256,0,stream>>>(x, xbf, stats);
  k_gn_apply2<<<4096,256,0,stream>>>(xbf, stats, gsc, gbi, hn);
  k_wtrans4<<<4096,256,0,stream>>>(wq, wk, wv, wo, wqkvT, woT);

  // QKV projection: q,k,v all fp8 out
  k_qkv<<<dim3(6,128,1),512,0,stream>>>(hn, wqkvT, q8, k8, v8, bq, bk, bv);

  const float scale = 0.044194173824159216f;  // 512^-0.5
  // QK^T fp8 -> fp8 P + row partials
  k_qk8<<<dim3(16,32,NB),512,0,stream>>>(q8, k8, P8, partsum, scale);
  k_sumred<<<NM/4,256,0,stream>>>(partsum, sums);
  // PV fp8 full-K, fused 1/rowsum scaling -> o directly (no opart / pvred)
  k_pv8f<<<dim3(4,32,NB),256,0,stream>>>(P8, v8, sums, o);
  // output projection + bias + residual
  k_t256o<<<dim3(4,128,1),256,0,stream>>>(o, woT, out, bo, x);
}

// Round 18
// 199.302 us; speedup vs baseline: 2.1319x; 1.0122x over previous
//
#include <hip/hip_runtime.h>
#include <stdint.h>

typedef unsigned short u16;
typedef long i64;
typedef __bf16 bf16x8 __attribute__((ext_vector_type(8)));
typedef float f32x4 __attribute__((ext_vector_type(4)));
typedef uint32_t u32x2 __attribute__((ext_vector_type(2)));
typedef uint32_t u32x4 __attribute__((ext_vector_type(4)));

#define NB 4
#define NC 512
#define NG 32
#define NSEQ 4096
#define NM (NB*NSEQ)

#define MFMA_(a,b,c) __builtin_amdgcn_mfma_f32_16x16x32_bf16(a,b,c,0,0,0)
#define MFMA8_(a,b,c) __builtin_amdgcn_mfma_f32_16x16x32_fp8_fp8(a,b,c,0,0,0)

__device__ __forceinline__ u16 f2bf(float f){
  uint32_t u = __builtin_bit_cast(uint32_t, f);
  u += 0x7FFFu + ((u >> 16) & 1u);
  return (u16)(u >> 16);
}
__device__ __forceinline__ float bfu(uint32_t lo16){
  return __builtin_bit_cast(float, lo16 << 16);
}
__device__ __forceinline__ uint32_t pk2(float a, float b){
  return (uint32_t)f2bf(a) | ((uint32_t)f2bf(b) << 16);
}

__device__ __forceinline__ void gll16(const void* g, void* l){
  __builtin_amdgcn_global_load_lds(
      (const __attribute__((address_space(1))) void*)g,
      (__attribute__((address_space(3))) void*)l, 16, 0, 0);
}

__global__ void k_zero(float* p, int n){
  int i = blockIdx.x*blockDim.x + threadIdx.x;
  if (i < n) p[i] = 0.f;
}

__global__ __launch_bounds__(256) void k_gn_stats2(const float* __restrict__ x,
    u16* __restrict__ xbf, float* __restrict__ stats){
  int blk = blockIdx.x;
  int b = blk >> 6, ch = blk & 63;
  int t = threadIdx.x;
  int colv = t & 127;
  int r0 = ch*64 + (t >> 7);
  const float* xp = x  + (size_t)b*NSEQ*NC + (size_t)r0*NC + colv*4;
  u16* xb       = xbf + (size_t)b*NSEQ*NC + (size_t)r0*NC + colv*4;
  float s1 = 0.f, s2 = 0.f;
  #pragma unroll 4
  for (int i = 0; i < 32; i++){
    float4 v = *(const float4*)(xp + (size_t)i*2*NC);
    s1 += v.x+v.y+v.z+v.w;
    s2 += v.x*v.x+v.y*v.y+v.z*v.z+v.w*v.w;
    ushort4 o; o.x=f2bf(v.x); o.y=f2bf(v.y); o.z=f2bf(v.z); o.w=f2bf(v.w);
    *(ushort4*)(xb + (size_t)i*2*NC) = o;
  }
  s1 += __shfl_xor(s1,1); s2 += __shfl_xor(s2,1);
  s1 += __shfl_xor(s1,2); s2 += __shfl_xor(s2,2);
  __shared__ float ls1[4][16], ls2[4][16];
  int w = t >> 6, l = t & 63;
  if ((l & 3) == 0){ ls1[w][l>>2] = s1; ls2[w][l>>2] = s2; }
  __syncthreads();
  if (t < 32){
    int g = t;
    int wlo = g >> 4;
    float a1 = ls1[wlo][g&15] + ls1[wlo+2][g&15];
    float a2 = ls2[wlo][g&15] + ls2[wlo+2][g&15];
    atomicAdd(&stats[(b*NG+g)*2+0], a1);
    atomicAdd(&stats[(b*NG+g)*2+1], a2);
  }
}

__global__ __launch_bounds__(256) void k_gn_apply2(const u16* __restrict__ xbf,
    const float* __restrict__ stats, const float* __restrict__ gsc,
    const float* __restrict__ gbi, u16* __restrict__ hn){
  const float inv_cnt = 1.f/((float)NSEQ*16.f);
  size_t i = ((size_t)blockIdx.x*256 + threadIdx.x)*8;
  int c = (int)(i & 511);
  int b = (int)(i >> 21);
  int g = c >> 4;
  float s1 = stats[(b*NG+g)*2], s2 = stats[(b*NG+g)*2+1];
  float mean = s1*inv_cnt;
  float rstd = rsqrtf(s2*inv_cnt - mean*mean + 1e-6f);
  u32x4 v = *(const u32x4*)(xbf + i);
  float4 scA = *(const float4*)(gsc + c), scB = *(const float4*)(gsc + c + 4);
  float4 biA = *(const float4*)(gbi + c), biB = *(const float4*)(gbi + c + 4);
  const float sc[8] = {scA.x,scA.y,scA.z,scA.w,scB.x,scB.y,scB.z,scB.w};
  const float bi[8] = {biA.x,biA.y,biA.z,biA.w,biB.x,biB.y,biB.z,biB.w};
  u32x4 o;
  #pragma unroll
  for (int j = 0; j < 4; j++){
    float lo = bfu(v[j] & 0xFFFFu);
    float hi = __builtin_bit_cast(float, v[j] & 0xFFFF0000u);
    o[j] = pk2((lo-mean)*rstd*sc[2*j] + bi[2*j], (hi-mean)*rstd*sc[2*j+1] + bi[2*j+1]);
  }
  *(u32x4*)(hn + i) = o;
}

__global__ __launch_bounds__(256) void k_wtrans4(const float* __restrict__ wq, const float* __restrict__ wk,
    const float* __restrict__ wv, const float* __restrict__ wo,
    u16* __restrict__ wqkvT, u16* __restrict__ woT){
  int j = blockIdx.x*256 + threadIdx.x;
  int wsel = j >> 18, r = j & 262143;
  int n = r >> 9, k = r & 511;
  const float* src = wsel==0?wq : wsel==1?wk : wsel==2?wv : wo;
  u16 v = f2bf(src[k*512 + n]);
  if (wsel < 3) wqkvT[(size_t)wsel*262144 + r] = v;
  else          woT[r] = v;
}

__global__ __launch_bounds__(256) void k_sumred(const float* __restrict__ part, float* __restrict__ sums){
  int row = blockIdx.x*4 + (threadIdx.x >> 6);
  int l = threadIdx.x & 63;
  float s = part[(size_t)row*64 + l];
  #pragma unroll
  for (int o = 32; o; o >>= 1) s += __shfl_xor(s, o);
  if (l == 0) sums[row] = s;
}

#define NTQ 16

__device__ __forceinline__ int dec_rl(int L, int p){ return 2*L + ((p>>2) ^ ((L>>1)&1)); }
__device__ __forceinline__ int dec_kq(int L, int p){
  int P01 = ((((L)&1)^((L>>2)&1))<<1) | (((L>>1)&1)^((L>>3)&1));
  return (p&3) ^ P01;
}
__device__ __forceinline__ int swz_off(int rl, int kq){
  int Pq = (((rl&1)^((rl>>2)&1))<<2) | ((((rl>>1)&1)^((rl>>3)&1))<<1) | (((rl>>2)&1)^((rl>>4)&1));
  return ((rl>>1)<<7) + ((Pq ^ kq)<<4);
}

__global__ __launch_bounds__(512, 4) void k_qkv(
    const u16* __restrict__ A, const u16* __restrict__ B,
    uint8_t* __restrict__ q8, uint8_t* __restrict__ k8, uint8_t* __restrict__ v8T,
    const float* __restrict__ bias0, const float* __restrict__ bias1, const float* __restrict__ bias2)
{
  __shared__ u16 LDS[36864];
  char* Lb = (char*)LDS;
  const int t = threadIdx.x;
  const int l = t & 63, w = t >> 6;
  const int wr = w >> 2, wc = w & 3;
  const int frow = l & 15, kq = l >> 4;
  const int nx = gridDim.x, ny = gridDim.y;
  int f = (int)blockIdx.y*nx + (int)blockIdx.x;
  const int nwg = nx*ny;
  f = (f & 7)*(nwg >> 3) + (f >> 3);
  const int bx = f % nx; const int by = f / nx;
  const int brow = by*128, bcol = bx*256;

  const int pA = t & 7;
  const int LA = t >> 3;
  const int LB0 = t >> 3, LB1 = 64 + (t >> 3);
  const int rlA  = dec_rl(LA, pA),  kqA  = dec_kq(LA, pA);
  const int rlB0 = dec_rl(LB0, pA), kqB0 = dec_kq(LB0, pA);
  const int rlB1 = dec_rl(LB1, pA), kqB1 = dec_kq(LB1, pA);
  const u16* Ap  = A + (size_t)(brow + rlA )*NC + kqA*8;
  const u16* Bp0 = B + (size_t)(bcol + rlB0)*NC + kqB0*8;
  const u16* Bp1 = B + (size_t)(bcol + rlB1)*NC + kqB1*8;

  auto stage = [&](int buf, int kt){
    const size_t ko = (size_t)kt*32;
    gll16(Bp0 + ko, Lb + buf*16384 + t*16);
    gll16(Bp1 + ko, Lb + buf*16384 + 8192 + t*16);
    gll16(Ap  + ko, Lb + 49152 + buf*8192 + t*16);
  };

  int offA[4], offB[4];
  #pragma unroll
  for (int m=0;m<4;m++) offA[m] = swz_off(wr*64 + m*16 + frow, kq);
  #pragma unroll
  for (int c=0;c<4;c++) offB[c] = swz_off(wc*64 + 4*frow + c, kq);

  f32x4 acc[4][4] = {};

  auto body = [&](int buf, int s){
    bf16x8 a4[4], b4[4];
    #pragma unroll
    for (int m=0;m<4;m++) a4[m] = *(const bf16x8*)(Lb + 49152 + buf*8192 + offA[m]);
    #pragma unroll
    for (int c=0;c<4;c++) b4[c] = *(const bf16x8*)(Lb + buf*16384 + offB[c]);
    const bool doStage = (s + 2 < NTQ);
    if (doStage){ int nb = buf+2; if (nb>=3) nb-=3; stage(nb, s+2); }
    asm volatile("s_waitcnt lgkmcnt(0)" ::: "memory");
    __builtin_amdgcn_sched_barrier(0);
    __builtin_amdgcn_s_setprio(1);
    #pragma unroll
    for (int m=0;m<4;m++)
      #pragma unroll
      for (int c=0;c<4;c++)
        acc[m][c] = MFMA_(a4[m], b4[c], acc[m][c]);
    __builtin_amdgcn_s_setprio(0);
    __builtin_amdgcn_sched_barrier(0);
    if (s + 1 < NTQ){
      if (doStage) asm volatile("s_waitcnt vmcnt(3)" ::: "memory");
      else         asm volatile("s_waitcnt vmcnt(0)" ::: "memory");
      __builtin_amdgcn_s_barrier();
    }
  };

  stage(0, 0); stage(1, 1);
  asm volatile("s_waitcnt vmcnt(3)" ::: "memory");
  __builtin_amdgcn_s_barrier();

  #pragma unroll
  for (int i = 0; i < 5; i++){
    body(0, i*3);
    body(1, i*3+1);
    body(2, i*3+2);
  }
  body(0, 15);

  const int col4 = wc*64 + 4*frow;
  const int seg = bcol >> 9;
  const int colr = (bcol & 511) + col4;
  if (seg < 2){
    uint8_t* dq = seg==0 ? q8 : k8;
    const float* bp = seg==0 ? bias0 : bias1;
    const float4 bi = *(const float4*)(bp + colr);
    #pragma unroll
    for (int m=0;m<4;m++){
      #pragma unroll
      for (int r=0;r<4;r++){
        const int rr = brow + wr*64 + m*16 + kq*4 + r;
        unsigned int pv = __builtin_amdgcn_cvt_pk_fp8_f32(acc[m][0][r]+bi.x, acc[m][1][r]+bi.y, 0u, false);
        pv = __builtin_amdgcn_cvt_pk_fp8_f32(acc[m][2][r]+bi.z, acc[m][3][r]+bi.w, pv, true);
        *(unsigned int*)&dq[(size_t)rr*NC + colr] = pv;
      }
    }
  } else {
    const float4 bi = *(const float4*)(bias2 + colr);
    const float bvs[4] = {bi.x, bi.y, bi.z, bi.w};
    #pragma unroll
    for (int m=0;m<4;m++){
      const int rr0 = brow + wr*64 + m*16 + kq*4;
      const int b = rr0 >> 12, sq = rr0 & 4095;
      #pragma unroll
      for (int n=0;n<4;n++){
        unsigned int pv = __builtin_amdgcn_cvt_pk_fp8_f32(acc[m][n][0]+bvs[n], acc[m][n][1]+bvs[n], 0u, false);
        pv = __builtin_amdgcn_cvt_pk_fp8_f32(acc[m][n][2]+bvs[n], acc[m][n][3]+bvs[n], pv, true);
        *(unsigned int*)&v8T[((size_t)(b*NC + colr + n) << 12) + sq] = pv;
      }
    }
  }
}

__device__ __forceinline__ int rdoff8(int rl, int ks){
  int slot8 = ((rl&1)<<3) | (((((ks>>1) ^ (rl>>1)) & 3))<<1) | (ks&1);
  return ((rl>>1)<<7) + (slot8<<3);
}
__device__ __forceinline__ int cmap64(int p){
  return (p & 192) + (((p & 15) << 2) | ((p >> 4) & 3));
}

__global__ __launch_bounds__(512, 4) void k_qk8(
    const uint8_t* __restrict__ Q8, const uint8_t* __restrict__ K8,
    uint8_t* __restrict__ P8, float* __restrict__ partsum, float alpha)
{
  __shared__ char LDS[73728];
  char* LA = LDS;
  char* LB = LDS + 24576;
  const int t = threadIdx.x;
  const int l = t & 63, w = t >> 6;
  const int wr = w >> 2, wc = w & 3;
  const int frow = l & 15, kq = l >> 4;
  int f = ((int)blockIdx.z*32 + (int)blockIdx.y)*16 + (int)blockIdx.x;
  f = (f & 7)*256 + (f >> 3);
  const int bx = f & 15; const int t2 = f >> 4;
  const int by = t2 & 31; const int bb = t2 >> 5;
  const int brow = by*128, bcol = bx*256;
  const size_t bOff = (size_t)bb*NSEQ*NC;

  const int Lp = t >> 3, p2 = t & 7;
  const int rlu = 2*Lp + (p2 >> 2);
  const int gru = (p2 & 3) ^ (Lp & 3);
  const uint8_t* Ap  = Q8 + bOff + (size_t)(brow + rlu)*NC + gru*16;
  const uint8_t* Bp0 = K8 + bOff + (size_t)(bcol + cmap64(rlu))*NC + gru*16;
  const uint8_t* Bp1 = K8 + bOff + (size_t)(bcol + cmap64(rlu + 128))*NC + gru*16;

  auto stage = [&](int buf, int kt){
    const size_t ko = (size_t)kt*64;
    gll16(Ap  + ko, LA + buf*8192 + t*16);
    gll16(Bp0 + ko, LB + buf*16384 + t*16);
    gll16(Bp1 + ko, LB + buf*16384 + 8192 + t*16);
  };

  int offA[4], offB[4];
  #pragma unroll
  for (int m=0;m<4;m++) offA[m] = rdoff8(wr*64 + m*16 + frow, kq);
  #pragma unroll
  for (int n=0;n<4;n++) offB[n] = rdoff8(wc*64 + n*16 + frow, kq);

  f32x4 acc[4][4] = {};

  auto body = [&](int buf, int s){
    i64 a0[4], a1[4], b0[4], b1[4];
    const char* Ab = LA + buf*8192;
    const char* Bb = LB + buf*16384;
    #pragma unroll
    for (int m=0;m<4;m++) a0[m] = *(const i64*)(Ab + offA[m]);
    #pragma unroll
    for (int n=0;n<4;n++) b0[n] = *(const i64*)(Bb + offB[n]);
    __builtin_amdgcn_sched_barrier(0);
    #pragma unroll
    for (int m=0;m<4;m++) a1[m] = *(const i64*)(Ab + (offA[m]^32));
    #pragma unroll
    for (int n=0;n<4;n++) b1[n] = *(const i64*)(Bb + (offB[n]^32));
    const bool doStage = (s + 2 < 8);
    if (doStage){ int nb = buf+2; if (nb>=3) nb-=3; stage(nb, s+2); }
    __builtin_amdgcn_sched_barrier(0);
    asm volatile("s_waitcnt lgkmcnt(8)" ::: "memory");
    __builtin_amdgcn_sched_barrier(0);
    __builtin_amdgcn_s_setprio(1);
    #pragma unroll
    for (int m=0;m<4;m++)
      #pragma unroll
      for (int n=0;n<4;n++)
        acc[m][n] = MFMA8_(a0[m], b0[n], acc[m][n]);
    __builtin_amdgcn_sched_barrier(0);
    asm volatile("s_waitcnt lgkmcnt(0)" ::: "memory");
    __builtin_amdgcn_sched_barrier(0);
    #pragma unroll
    for (int m=0;m<4;m++)
      #pragma unroll
      for (int n=0;n<4;n++)
        acc[m][n] = MFMA8_(a1[m], b1[n], acc[m][n]);
    __builtin_amdgcn_s_setprio(0);
    __builtin_amdgcn_sched_barrier(0);
    if (s + 1 < 8){
      if (doStage) asm volatile("s_waitcnt vmcnt(3)" ::: "memory");
      else         asm volatile("s_waitcnt vmcnt(0)" ::: "memory");
      __builtin_amdgcn_s_barrier();
    }
  };

  stage(0, 0); stage(1, 1);
  asm volatile("s_waitcnt vmcnt(3)" ::: "memory");
  __builtin_amdgcn_s_barrier();

  body(0,0); body(1,1); body(2,2); body(0,3);
  body(1,4); body(2,5); body(0,6); body(1,7);

  uint8_t* Pp = P8 + (size_t)bb*NSEQ*NSEQ;
  const int colp = bcol + wc*64 + 4*frow;
  #pragma unroll
  for (int m=0;m<4;m++){
    #pragma unroll
    for (int r=0;r<4;r++){
      const int rr = brow + wr*64 + m*16 + kq*4 + r;
      float e0 = __expf(alpha*acc[m][0][r]);
      float e1 = __expf(alpha*acc[m][1][r]);
      float e2 = __expf(alpha*acc[m][2][r]);
      float e3 = __expf(alpha*acc[m][3][r]);
      unsigned int p4 = __builtin_amdgcn_cvt_pk_fp8_f32(e0, e1, 0u, false);
      p4 = __builtin_amdgcn_cvt_pk_fp8_f32(e2, e3, p4, true);
      __builtin_nontemporal_store(p4, (unsigned int*)&Pp[(size_t)rr*NSEQ + colp]);
      float rs = e0 + e1 + e2 + e3;
      rs += __shfl_xor(rs, 1); rs += __shfl_xor(rs, 2);
      rs += __shfl_xor(rs, 4); rs += __shfl_xor(rs, 8);
      if (frow == 0)
        partsum[((size_t)bb*NSEQ + rr)*64 + bx*4 + wc] = rs;
    }
  }
}

__global__ __launch_bounds__(256, 3) void k_pv8f(
    const uint8_t* __restrict__ P8, const uint8_t* __restrict__ V8,
    const float* __restrict__ sums, u16* __restrict__ o)
{
  __shared__ char LDS[49152];
  char* Lb = LDS;
  const int t = threadIdx.x;
  const int l = t & 63, w = t >> 6;
  const int wr = w >> 1, wc = w & 1;
  const int frow = l & 15, kq = l >> 4;
  int f = ((int)blockIdx.z*32 + (int)blockIdx.y)*4 + (int)blockIdx.x;
  f = (f & 7)*64 + (f >> 3);
  const int bx = f & 3; const int t2 = f >> 2;
  const int by = t2 & 31; const int bb = t2 >> 5;
  const int brow = by*128, bcol = bx*128;

  const int Lp = t >> 3, p2 = t & 7;
  const int rlu = 2*Lp + (p2 >> 2);
  const int gru = (p2 & 3) ^ (Lp & 3);
  const uint8_t* Ap0 = P8 + (size_t)bb*NSEQ*NSEQ + (size_t)(brow + rlu)*NSEQ + gru*16;
  const uint8_t* Ap1 = P8 + (size_t)bb*NSEQ*NSEQ + (size_t)(brow + rlu + 64)*NSEQ + gru*16;
  const uint8_t* Bp0 = V8 + (size_t)bb*NC*NSEQ + (size_t)(bcol + cmap64(rlu))*NSEQ + gru*16;
  const uint8_t* Bp1 = V8 + (size_t)bb*NC*NSEQ + (size_t)(bcol + cmap64(rlu + 64))*NSEQ + gru*16;

  auto stage = [&](int buf, int kt){
    const size_t ko = (size_t)kt*64;
    gll16(Ap0 + ko, Lb + buf*16384 + t*16);
    gll16(Ap1 + ko, Lb + buf*16384 + 4096 + t*16);
    gll16(Bp0 + ko, Lb + buf*16384 + 8192 + t*16);
    gll16(Bp1 + ko, Lb + buf*16384 + 12288 + t*16);
  };

  int offA[4], offB[4];
  #pragma unroll
  for (int m=0;m<4;m++) offA[m] = rdoff8(wr*64 + m*16 + frow, kq);
  #pragma unroll
  for (int n=0;n<4;n++) offB[n] = rdoff8(wc*64 + n*16 + frow, kq);

  f32x4 acc[4][4] = {};

  auto body = [&](int buf, int s){
    i64 a0[4], a1[4], b0[4], b1[4];
    const char* Ab = Lb + buf*16384;
    const char* Bb = Lb + buf*16384 + 8192;
    #pragma unroll
    for (int m=0;m<4;m++) a0[m] = *(const i64*)(Ab + offA[m]);
    #pragma unroll
    for (int n=0;n<4;n++) b0[n] = *(const i64*)(Bb + offB[n]);
    __builtin_amdgcn_sched_barrier(0);
    #pragma unroll
    for (int m=0;m<4;m++) a1[m] = *(const i64*)(Ab + (offA[m]^32));
    #pragma unroll
    for (int n=0;n<4;n++) b1[n] = *(const i64*)(Bb + (offB[n]^32));
    const bool doStage = (s + 2 < 64);
    if (doStage){ int nb = buf+2; if (nb>=3) nb-=3; stage(nb, s+2); }
    __builtin_amdgcn_sched_barrier(0);
    asm volatile("s_waitcnt lgkmcnt(8)" ::: "memory");
    __builtin_amdgcn_sched_barrier(0);
    __builtin_amdgcn_s_setprio(1);
    #pragma unroll
    for (int m=0;m<4;m++)
      #pragma unroll
      for (int n=0;n<4;n++)
        acc[m][n] = MFMA8_(a0[m], b0[n], acc[m][n]);
    __builtin_amdgcn_sched_barrier(0);
    asm volatile("s_waitcnt lgkmcnt(0)" ::: "memory");
    __builtin_amdgcn_sched_barrier(0);
    #pragma unroll
    for (int m=0;m<4;m++)
      #pragma unroll
      for (int n=0;n<4;n++)
        acc[m][n] = MFMA8_(a1[m], b1[n], acc[m][n]);
    __builtin_amdgcn_s_setprio(0);
    __builtin_amdgcn_sched_barrier(0);
    if (s + 1 < 64){
      if (doStage) asm volatile("s_waitcnt vmcnt(4)" ::: "memory");
      else         asm volatile("s_waitcnt vmcnt(0)" ::: "memory");
      __builtin_amdgcn_s_barrier();
    }
  };

  stage(0, 0); stage(1, 1);
  asm volatile("s_waitcnt vmcnt(4)" ::: "memory");
  __builtin_amdgcn_s_barrier();

  #pragma unroll 1
  for (int i = 0; i < 21; i++){
    body(0, i*3);
    body(1, i*3+1);
    body(2, i*3+2);
  }
  body(0, 63);

  u16* op = o + (size_t)bb*NSEQ*NC;
  const int col4 = bcol + wc*64 + 4*frow;
  #pragma unroll
  for (int m=0;m<4;m++){
    #pragma unroll
    for (int r=0;r<4;r++){
      const int rr = brow + wr*64 + m*16 + kq*4 + r;
      const float inv = 1.f/sums[(size_t)bb*NSEQ + rr];
      u32x2 wv;
      wv[0] = pk2(acc[m][0][r]*inv, acc[m][1][r]*inv);
      wv[1] = pk2(acc[m][2][r]*inv, acc[m][3][r]*inv);
      __builtin_nontemporal_store(wv, (u32x2*)&op[(size_t)rr*NC + col4]);
    }
  }
}

__global__ __launch_bounds__(256, 3) void k_t256o(
    const u16* __restrict__ A, const u16* __restrict__ B,
    float* __restrict__ out, const float* __restrict__ bias, const float* __restrict__ res)
{
  __shared__ u16 LDS[24576];
  char* Lb = (char*)LDS;
  const int t = threadIdx.x;
  const int l = t & 63, w = t >> 6;
  const int wr = w >> 1, wc = w & 1;
  const int frow = l & 15, kq = l >> 4;
  int f = (int)blockIdx.y*4 + (int)blockIdx.x;
  f = (f & 7)*64 + (f >> 3);
  const int bx = f & 3; const int by = f >> 2;
  const int brow = by*128, bcol = bx*128;

  const int pA = t & 7;
  const int L0 = t >> 3;
  const int rl0 = dec_rl(L0, pA),      kq0 = dec_kq(L0, pA);
  const int rl1 = dec_rl(L0+32, pA),   kq1 = dec_kq(L0+32, pA);
  const u16* Ap0 = A + (size_t)(brow + rl0)*NC + kq0*8;
  const u16* Ap1 = A + (size_t)(brow + rl1)*NC + kq1*8;
  const u16* Bp0 = B + (size_t)(bcol + rl0)*NC + kq0*8;
  const u16* Bp1 = B + (size_t)(bcol + rl1)*NC + kq1*8;

  auto stage = [&](int buf, int kt){
    const size_t ko = (size_t)kt*32;
    gll16(Ap0 + ko, Lb + buf*16384 + t*16);
    gll16(Ap1 + ko, Lb + buf*16384 + 4096 + t*16);
    gll16(Bp0 + ko, Lb + buf*16384 + 8192 + t*16);
    gll16(Bp1 + ko, Lb + buf*16384 + 12288 + t*16);
  };

  int offA[4], offB[4];
  #pragma unroll
  for (int m=0;m<4;m++) offA[m] = swz_off(wr*64 + m*16 + frow, kq);
  #pragma unroll
  for (int c=0;c<4;c++) offB[c] = swz_off(wc*64 + 4*frow + c, kq);

  f32x4 acc[4][4] = {};

  auto body = [&](int buf, int s){
    bf16x8 a4[4], b4[4];
    #pragma unroll
    for (int m=0;m<4;m++) a4[m] = *(const bf16x8*)(Lb + buf*16384 + offA[m]);
    #pragma unroll
    for (int c=0;c<4;c++) b4[c] = *(const bf16x8*)(Lb + buf*16384 + 8192 + offB[c]);
    const bool doStage = (s + 2 < NTQ);
    if (doStage){ int nb = buf+2; if (nb>=3) nb-=3; stage(nb, s+2); }
    asm volatile("s_waitcnt lgkmcnt(0)" ::: "memory");
    __builtin_amdgcn_sched_barrier(0);
    __builtin_amdgcn_s_setprio(1);
    #pragma unroll
    for (int m=0;m<4;m++)
      #pragma unroll
      for (int c=0;c<4;c++)
        acc[m][c] = MFMA_(a4[m], b4[c], acc[m][c]);
    __builtin_amdgcn_s_setprio(0);
    __builtin_amdgcn_sched_barrier(0);
    if (s + 1 < NTQ){
      if (doStage) asm volatile("s_waitcnt vmcnt(4)" ::: "memory");
      else         asm volatile("s_waitcnt vmcnt(0)" ::: "memory");
      __builtin_amdgcn_s_barrier();
    }
  };

  stage(0, 0); stage(1, 1);
  asm volatile("s_waitcnt vmcnt(4)" ::: "memory");
  __builtin_amdgcn_s_barrier();

  #pragma unroll
  for (int i = 0; i < 5; i++){
    body(0, i*3);
    body(1, i*3+1);
    body(2, i*3+2);
  }
  body(0, 15);

  const int c = bcol + wc*64 + 4*frow;
  const float4 bi = *(const float4*)(bias + c);
  #pragma unroll
  for (int m=0;m<4;m++){
    #pragma unroll
    for (int r=0;r<4;r++){
      const int rr = brow + wr*64 + m*16 + kq*4 + r;
      const float4 rv = *(const float4*)(res + (size_t)rr*NC + c);
      float4 ov;
      ov.x = acc[m][0][r] + bi.x + rv.x;
      ov.y = acc[m][1][r] + bi.y + rv.y;
      ov.z = acc[m][2][r] + bi.z + rv.z;
      ov.w = acc[m][3][r] + bi.w + rv.w;
      *(float4*)&out[(size_t)rr*NC + c] = ov;
    }
  }
}

extern "C" void kernel_launch(void* const* d_in, const int* in_sizes, int n_in,
                              void* d_out, int out_size, void* d_ws, size_t ws_size,
                              hipStream_t stream){
  const float* x   = (const float*)d_in[0];
  const float* gsc = (const float*)d_in[1];
  const float* gbi = (const float*)d_in[2];
  const float* wq  = (const float*)d_in[3];
  const float* bq  = (const float*)d_in[4];
  const float* wk  = (const float*)d_in[5];
  const float* bk  = (const float*)d_in[6];
  const float* wv  = (const float*)d_in[7];
  const float* bv  = (const float*)d_in[8];
  const float* wo  = (const float*)d_in[9];
  const float* bo  = (const float*)d_in[10];
  float* out = (float*)d_out;

  char* wsp = (char*)d_ws;
  size_t off = 0;
  auto alloc = [&](size_t bytes)->void*{ void* p = wsp + off; off += (bytes + 255) & ~(size_t)255; return p; };
  float* stats   = (float*)alloc((size_t)NB*NG*2*sizeof(float));
  float* sums    = (float*)alloc((size_t)NM*sizeof(float));
  float* partsum = (float*)alloc((size_t)NM*64*sizeof(float));
  u16* xbf   = (u16*)alloc((size_t)NM*NC*2);
  u16* hn    = (u16*)alloc((size_t)NM*NC*2);
  u16* wqkvT = (u16*)alloc((size_t)3*NC*NC*2);
  u16* woT   = (u16*)alloc((size_t)NC*NC*2);
  uint8_t* q8 = (uint8_t*)alloc((size_t)NM*NC);
  uint8_t* k8 = (uint8_t*)alloc((size_t)NM*NC);
  uint8_t* v8 = (uint8_t*)alloc((size_t)NM*NC);
  u16* o     = (u16*)alloc((size_t)NM*NC*2);
  uint8_t* P8 = (uint8_t*)alloc((size_t)NB*NSEQ*NSEQ);

  k_zero<<<1,256,0,stream>>>(stats, NB*NG*2);
  k_gn_stats2<<<NB*64,256,0,stream>>>(x, xbf, stats);
  k_gn_apply2<<<4096,256,0,stream>>>(xbf, stats, gsc, gbi, hn);
  k_wtrans4<<<4096,256,0,stream>>>(wq, wk, wv, wo, wqkvT, woT);

  k_qkv<<<dim3(6,128,1),512,0,stream>>>(hn, wqkvT, q8, k8, v8, bq, bk, bv);

  const float scale = 0.044194173824159216f;
  k_qk8<<<dim3(16,32,NB),512,0,stream>>>(q8, k8, P8, partsum, scale);
  k_sumred<<<NM/4,256,0,stream>>>(partsum, sums);
  k_pv8f<<<dim3(4,32,NB),256,0,stream>>>(P8, v8, sums, o);
  k_t256o<<<dim3(4,128,1),256,0,stream>>>(o, woT, out, bo, x);
}